// Round 4
// baseline (1438.096 us; speedup 1.0000x reference)
//
#include <hip/hip_runtime.h>
#include <stdint.h>

// GraphECL loss on MI355X. N=10000, E=330000, IN=512, HID=OUT=256.
// TEMP=0.5, LAM=1e-3, LAMBDA_LOSS=1, BN_EPS=1e-5.

#define TEMP_INV 2.0f
#define LAMC 1.0e-3f
// sqrt(log2(e)/TEMP): folded into bf16 z/q so MFMA acc == exp2 argument
#define SSCALE 1.6986436f

typedef __attribute__((ext_vector_type(8))) __bf16 bf16x8;
typedef __attribute__((ext_vector_type(4))) float f32x4;

__device__ __forceinline__ unsigned short f2bf(float x) {
  union { float f; unsigned int u; } v; v.f = x;
  unsigned int r = v.u + 0x7FFFu + ((v.u >> 16) & 1u);
  return (unsigned short)(r >> 16);
}

__device__ __forceinline__ void g2lds16(const void* gc, void* l) {
  void* g = const_cast<void*>(gc);
  __builtin_amdgcn_global_load_lds(
      (__attribute__((address_space(1))) void*)g,
      (__attribute__((address_space(3))) void*)l, 16, 0, 0);
}

// ---------------- degrees ----------------
__global__ void k_deg(const int* __restrict__ src, const int* __restrict__ dst,
                      float* deg_out, float* deg_in, int E) {
  int i = blockIdx.x * blockDim.x + threadIdx.x;
  if (i < E) {
    atomicAdd(&deg_out[src[i]], 1.0f);
    atomicAdd(&deg_in[dst[i]], 1.0f);
  }
}

__global__ void k_rdeg(const float* __restrict__ deg_out, const float* __restrict__ deg_in,
                       float* rdo, float* rdi, float* idi, int N) {
  int i = blockIdx.x * blockDim.x + threadIdx.x;
  if (i < N) {
    float o = deg_out[i], d = deg_in[i];
    rdo[i] = rsqrtf(o);
    rdi[i] = rsqrtf(d);
    idi[i] = 1.0f / d;  // self loops guarantee d >= 1
  }
}

// exclusive prefix sum of deg_in (ints stored as exact floats); 1 block, 1024 thr
__global__ void k_scan(const float* __restrict__ deg, int* __restrict__ off, int N, int E) {
  __shared__ int sm[1024];
  int tid = threadIdx.x;
  int chunk = (N + 1023) / 1024;
  int b = tid * chunk;
  int sum = 0;
  for (int j = 0; j < chunk; j++) { int i = b + j; if (i < N) sum += (int)deg[i]; }
  sm[tid] = sum;
  __syncthreads();
  for (int s = 1; s < 1024; s <<= 1) {
    int v = (tid >= s) ? sm[tid - s] : 0;
    __syncthreads();
    sm[tid] += v;
    __syncthreads();
  }
  int run = (tid == 0) ? 0 : sm[tid - 1];
  for (int j = 0; j < chunk; j++) {
    int i = b + j;
    if (i < N) { off[i] = run; run += (int)deg[i]; }
  }
  if (tid == 0) off[N] = E;
}

__global__ void k_fill(const int* __restrict__ src, const int* __restrict__ dst,
                       const int* __restrict__ off, int* cur,
                       const float* __restrict__ rdo, const float* __restrict__ rdi,
                       int* adj, float* aw, int E) {
  int e = blockIdx.x * blockDim.x + threadIdx.x;
  if (e < E) {
    int u = src[e], v = dst[e];
    int slot = off[v] + atomicAdd(&cur[v], 1);
    adj[slot] = u;
    aw[slot] = rdo[u] * rdi[v];  // symmetric GCN norm per edge
  }
}

// ------- no-LDS fp32 GEMM: C[M,256] = A[M,K] @ W[K,256] (+bias) -------
// BM=32 -> 313 blocks (all CUs covered). Thread = 2 rows x 16 contiguous cols.
// W streamed from L1/L2 (16-way lane dedupe: 1KB/k per wave); A per-lane rows.
// No LDS, no barriers -> no drain stalls. In-place (C==A) safe: each thread
// reads only its own 2 rows, stores them at the end.
template <int K, bool BIAS>
__global__ __launch_bounds__(256, 4) void k_gemmG(const float* __restrict__ A,
                                                  const float* __restrict__ W,
                                                  const float* __restrict__ bias,
                                                  float* __restrict__ C, int M) {
  int tid = threadIdx.x;
  int rg = tid >> 4, cg = tid & 15;
  int row0 = blockIdx.x * 32 + rg * 2;
  int c0 = cg * 16;
  int r0 = row0 < M ? row0 : M - 1;
  int r1 = row0 + 1 < M ? row0 + 1 : M - 1;
  const float* Ar0 = A + (size_t)r0 * K;
  const float* Ar1 = A + (size_t)r1 * K;
  float acc[2][16] = {};
  for (int k4 = 0; k4 < K; k4 += 4) {
    float4 a0 = *(const float4*)(Ar0 + k4);
    float4 a1 = *(const float4*)(Ar1 + k4);
    float a0v[4] = {a0.x, a0.y, a0.z, a0.w};
    float a1v[4] = {a1.x, a1.y, a1.z, a1.w};
    const float* wk = W + (size_t)k4 * 256 + c0;
#pragma unroll
    for (int i = 0; i < 4; i++) {
#pragma unroll
      for (int t = 0; t < 4; t++) {
        float4 w4 = *(const float4*)(wk + i * 256 + t * 4);
        acc[0][4 * t + 0] += a0v[i] * w4.x; acc[0][4 * t + 1] += a0v[i] * w4.y;
        acc[0][4 * t + 2] += a0v[i] * w4.z; acc[0][4 * t + 3] += a0v[i] * w4.w;
        acc[1][4 * t + 0] += a1v[i] * w4.x; acc[1][4 * t + 1] += a1v[i] * w4.y;
        acc[1][4 * t + 2] += a1v[i] * w4.z; acc[1][4 * t + 3] += a1v[i] * w4.w;
      }
    }
  }
#pragma unroll
  for (int r = 0; r < 2; r++) {
    int rr = row0 + r;
    if (rr < M) {
      float* crow = C + (size_t)rr * 256 + c0;
#pragma unroll
      for (int t = 0; t < 4; t++) {
        float4 v = {acc[r][4 * t], acc[r][4 * t + 1], acc[r][4 * t + 2], acc[r][4 * t + 3]};
        if constexpr (BIAS) {
          float4 b4 = *(const float4*)(bias + c0 + 4 * t);
          v.x += b4.x; v.y += b4.y; v.z += b4.z; v.w += b4.w;
        }
        *(float4*)(crow + t * 4) = v;
      }
    }
  }
}

// ------- fused dual no-LDS GEMM (same A): C1 = A@W1, C2 = A@W2 + b2. K=512. ----
__global__ __launch_bounds__(256, 2) void k_gemm2G(const float* __restrict__ A,
                                                   const float* __restrict__ W1f,
                                                   const float* __restrict__ W2f,
                                                   const float* __restrict__ b2f,
                                                   float* __restrict__ C1, float* __restrict__ C2,
                                                   int M) {
  int tid = threadIdx.x;
  int rg = tid >> 4, cg = tid & 15;
  int row0 = blockIdx.x * 32 + rg * 2;
  int c0 = cg * 16;
  int r0 = row0 < M ? row0 : M - 1;
  int r1 = row0 + 1 < M ? row0 + 1 : M - 1;
  const float* Ar0 = A + (size_t)r0 * 512;
  const float* Ar1 = A + (size_t)r1 * 512;
  float acc1[2][16] = {};
  float acc2[2][16] = {};
  for (int k4 = 0; k4 < 512; k4 += 4) {
    float4 a0 = *(const float4*)(Ar0 + k4);
    float4 a1 = *(const float4*)(Ar1 + k4);
    float a0v[4] = {a0.x, a0.y, a0.z, a0.w};
    float a1v[4] = {a1.x, a1.y, a1.z, a1.w};
    const float* wk1 = W1f + (size_t)k4 * 256 + c0;
    const float* wk2 = W2f + (size_t)k4 * 256 + c0;
#pragma unroll
    for (int i = 0; i < 4; i++) {
#pragma unroll
      for (int t = 0; t < 4; t++) {
        float4 w4 = *(const float4*)(wk1 + i * 256 + t * 4);
        float4 u4 = *(const float4*)(wk2 + i * 256 + t * 4);
        acc1[0][4 * t + 0] += a0v[i] * w4.x; acc1[0][4 * t + 1] += a0v[i] * w4.y;
        acc1[0][4 * t + 2] += a0v[i] * w4.z; acc1[0][4 * t + 3] += a0v[i] * w4.w;
        acc1[1][4 * t + 0] += a1v[i] * w4.x; acc1[1][4 * t + 1] += a1v[i] * w4.y;
        acc1[1][4 * t + 2] += a1v[i] * w4.z; acc1[1][4 * t + 3] += a1v[i] * w4.w;
        acc2[0][4 * t + 0] += a0v[i] * u4.x; acc2[0][4 * t + 1] += a0v[i] * u4.y;
        acc2[0][4 * t + 2] += a0v[i] * u4.z; acc2[0][4 * t + 3] += a0v[i] * u4.w;
        acc2[1][4 * t + 0] += a1v[i] * u4.x; acc2[1][4 * t + 1] += a1v[i] * u4.y;
        acc2[1][4 * t + 2] += a1v[i] * u4.z; acc2[1][4 * t + 3] += a1v[i] * u4.w;
      }
    }
  }
#pragma unroll
  for (int r = 0; r < 2; r++) {
    int rr = row0 + r;
    if (rr < M) {
#pragma unroll
      for (int t = 0; t < 4; t++) {
        float4 v1 = {acc1[r][4 * t], acc1[r][4 * t + 1], acc1[r][4 * t + 2], acc1[r][4 * t + 3]};
        float4 v2 = {acc2[r][4 * t], acc2[r][4 * t + 1], acc2[r][4 * t + 2], acc2[r][4 * t + 3]};
        float4 b4 = *(const float4*)(b2f + c0 + 4 * t);
        v2.x += b4.x; v2.y += b4.y; v2.z += b4.z; v2.w += b4.w;
        *(float4*)(C1 + (size_t)rr * 256 + c0 + 4 * t) = v1;
        *(float4*)(C2 + (size_t)rr * 256 + c0 + 4 * t) = v2;
      }
    }
  }
}

// ---------------- BatchNorm (train) stats + apply + relu ----------------
__global__ void k_bnstat(const float* __restrict__ T, float* s, float* ss, int M) {
  int c = threadIdx.x;
  int r0 = blockIdx.x * 64;
  float a = 0, b = 0;
  for (int r = r0; r < r0 + 64 && r < M; r++) {
    float v = T[(size_t)r * 256 + c];
    a += v; b += v * v;
  }
  atomicAdd(&s[c], a);
  atomicAdd(&ss[c], b);
}

__global__ void k_bnrelu(float* T, const float* __restrict__ s, const float* __restrict__ ss,
                         const float* __restrict__ g, const float* __restrict__ b, int M) {
  int r = blockIdx.x, c = threadIdx.x;
  float invM = 1.0f / (float)M;
  float mu = s[c] * invM;
  float var = ss[c] * invM - mu * mu;   // biased var, matches jnp.var
  float w = rsqrtf(var + 1e-5f) * g[c];
  float v = T[(size_t)r * 256 + c];
  v = (v - mu) * w + b[c];
  T[(size_t)r * 256 + c] = fmaxf(v, 0.0f);
}

// ---------------- CSR gather-aggregate: Y[v] = sum_{in-edges} w * X[src] (+bias)(relu) ---------
template <bool UNIT, bool RELU>
__global__ __launch_bounds__(256) void k_agg(const float* __restrict__ X, const int* __restrict__ off,
                                             const int* __restrict__ adj, const float* __restrict__ w,
                                             const float* __restrict__ bias, float* __restrict__ Y, int N) {
  int wv = threadIdx.x >> 6, ln = threadIdx.x & 63;
  int v = blockIdx.x * 4 + wv;
  if (v >= N) return;
  int s0 = off[v], s1 = off[v + 1];
  const float4* X4 = (const float4*)X;
  float4 acc = {0, 0, 0, 0};
  for (int s = s0; s < s1; s++) {
    int u = adj[s];
    float wt = UNIT ? 1.0f : w[s];
    float4 x = X4[(size_t)u * 64 + ln];
    acc.x += wt * x.x; acc.y += wt * x.y; acc.z += wt * x.z; acc.w += wt * x.w;
  }
  if constexpr (!UNIT) {
    float4 b = ((const float4*)bias)[ln];
    acc.x += b.x; acc.y += b.y; acc.z += b.z; acc.w += b.w;
  }
  if constexpr (RELU) {
    acc.x = fmaxf(acc.x, 0.f); acc.y = fmaxf(acc.y, 0.f);
    acc.z = fmaxf(acc.z, 0.f); acc.w = fmaxf(acc.w, 0.f);
  }
  ((float4*)Y)[(size_t)v * 64 + ln] = acc;
}

// ---------------- row L2-normalize (in place) + scaled bf16 copy; zero pad rows -----------
__global__ __launch_bounds__(256) void k_norm(float* X, unsigned short* Xb, int N, int NPAD) {
  int wv = threadIdx.x >> 6, ln = threadIdx.x & 63;
  int r = blockIdx.x * 4 + wv;
  if (r >= NPAD) return;
  if (r >= N) {  // exact zeros -> each pad j-row adds exp2(0)=1, corrected in k_final
    ushort4 z = {0, 0, 0, 0};
    ((ushort4*)Xb)[(size_t)r * 64 + ln] = z;
    return;
  }
  float4 x = ((const float4*)X)[(size_t)r * 64 + ln];
  float ss = x.x * x.x + x.y * x.y + x.z * x.z + x.w * x.w;
#pragma unroll
  for (int m = 1; m < 64; m <<= 1) ss += __shfl_xor(ss, m, 64);
  float sc = 1.0f / fmaxf(sqrtf(ss), 1e-12f);
  float4 xn = {x.x * sc, x.y * sc, x.z * sc, x.w * sc};
  ((float4*)X)[(size_t)r * 64 + ln] = xn;
  float bs = sc * SSCALE;
  ushort4 b;
  b.x = f2bf(x.x * bs); b.y = f2bf(x.y * bs);
  b.z = f2bf(x.z * bs); b.w = f2bf(x.w * bs);
  ((ushort4*)Xb)[(size_t)r * 64 + ln] = b;
}

// ---------------- similarity row-sums: S1[i]=sum_j exp(z_i.z_j/T), S2[i]=sum_j exp(z_i.q_j/T) ---
// 256 i-rows/block (4 waves x 64 rows, rf=4 -> 64 FLOP per LDS byte), A-frags
// loaded per-lane from global (once per block). j-tiles of 32 Z + 32 Q rows,
// double-buffered in LDS (2 x 32 KB); STAGE(t+1) issued BEFORE COMPUTE(t) so
// L2/L3 staging latency hides under ~2500 cy of MFMA (T3-minimum pipeline,
// one barrier per tile). XOR swizzle byte^=((row&7)<<4) on global source +
// ds_read address (linear LDS dest), bank-group uniform for all reads.
__global__ __launch_bounds__(256, 2) void k_sim(const unsigned short* __restrict__ Zb,
                                                const unsigned short* __restrict__ Qb,
                                                float* __restrict__ S1, float* __restrict__ S2,
                                                int N, int JT, int JS) {
  __shared__ __align__(1024) char LB[2][32768];
  const int tid = threadIdx.x;
  const int wv = tid >> 6, ln = tid & 63;
  const int i0 = blockIdx.x * 256;
  const int wb = wv * 64;

  auto STAGE = [&](int jt, int b) {
    int j0 = jt * 32;
    char* Lb = (char*)LB[b];
#pragma unroll
    for (int it = 0; it < 8; it++) {
      int c = it * 4 + wv;                 // 1KB chunk = 2 rows
      int L = c * 1024 + ln * 16;
      int r = L >> 9;                      // 0..31 = Z rows, 32..63 = Q rows
      int o = (L & 511) ^ ((r & 7) << 4);
      const char* g = (r < 32) ? (const char*)Zb + (size_t)(j0 + r) * 512 + o
                               : (const char*)Qb + (size_t)(j0 + r - 32) * 512 + o;
      g2lds16(g, Lb + c * 1024);
    }
  };

  int jt0 = (blockIdx.y * JT) / JS;
  int jt1 = ((blockIdx.y + 1) * JT) / JS;

  STAGE(jt0, 0);

  // A fragments from global: wave owns rows i0+wb .. +63 (4 rowfrags), K=256
  bf16x8 af[4][8];
#pragma unroll
  for (int rf = 0; rf < 4; rf++) {
    const char* arow = (const char*)(Zb + (size_t)(i0 + wb + rf * 16 + (ln & 15)) * 256);
#pragma unroll
    for (int kk = 0; kk < 8; kk++)
      af[rf][kk] = *(const bf16x8*)(arow + kk * 64 + ((ln >> 4) << 4));
  }

  f32x4 rs[4][2] = {};  // per-lane row-sum accumulators [rowfrag][mat]

  __syncthreads();      // tile jt0 staged (vmcnt drained at barrier)
  int cur = 0;
  for (int jt = jt0; jt < jt1; jt++) {
    if (jt + 1 < jt1) STAGE(jt + 1, cur ^ 1);   // prefetch overlaps compute
    const char* Lb = (const char*)LB[cur];
#pragma unroll
    for (int m = 0; m < 2; m++) {
      f32x4 acc[4][2] = {};
#pragma unroll
      for (int kk = 0; kk < 8; kk++) {
#pragma unroll
        for (int cf = 0; cf < 2; cf++) {
          int brow = m * 32 + cf * 16 + (ln & 15);
          int o = (kk * 64 + ((ln >> 4) << 4)) ^ ((brow & 7) << 4);
          bf16x8 bb = *(const bf16x8*)(Lb + brow * 512 + o);
#pragma unroll
          for (int rf = 0; rf < 4; rf++)
            acc[rf][cf] = __builtin_amdgcn_mfma_f32_16x16x32_bf16(af[rf][kk], bb, acc[rf][cf], 0, 0, 0);
        }
      }
#pragma unroll
      for (int rf = 0; rf < 4; rf++)
#pragma unroll
        for (int i = 0; i < 4; i++)
          rs[rf][m][i] += exp2f(acc[rf][0][i]) + exp2f(acc[rf][1][i]);
    }
    __syncthreads();    // next tile staged; this tile fully consumed
    cur ^= 1;
  }

  // reduce the 16 lanes (same ln>>4 group) sharing each output row; row=(ln>>4)*4+i
#pragma unroll
  for (int rf = 0; rf < 4; rf++)
#pragma unroll
    for (int m = 0; m < 2; m++)
#pragma unroll
      for (int i = 0; i < 4; i++) {
        float v = rs[rf][m][i];
        v += __shfl_xor(v, 1, 64);
        v += __shfl_xor(v, 2, 64);
        v += __shfl_xor(v, 4, 64);
        v += __shfl_xor(v, 8, 64);
        if ((ln & 15) == 0) {
          int row = i0 + wb + rf * 16 + ((ln >> 4) << 2) + i;
          if (row < N) atomicAdd(((m == 0) ? S1 : S2) + row, v);
        }
      }
}

// ---------------- final loss ----------------
__global__ __launch_bounds__(256) void k_final(const float* __restrict__ zsum, const float* __restrict__ q,
                                               const float* __restrict__ S1, const float* __restrict__ S2,
                                               const int* __restrict__ off, const int* __restrict__ adj,
                                               const float* __restrict__ idi, float* __restrict__ out,
                                               int N, float pad) {
  int wv = threadIdx.x >> 6, ln = threadIdx.x & 63;
  int v = blockIdx.x * 4 + wv;
  if (v >= N) return;
  float4 zs = ((const float4*)zsum)[(size_t)v * 64 + ln];
  float4 qv = ((const float4*)q)[(size_t)v * 64 + ln];
  float d = zs.x * qv.x + zs.y * qv.y + zs.z * qv.z + zs.w * qv.w;
  float s1v = S1[v] - pad;  // remove pad-row exp2(0)=1 contributions
  float lg = 0.0f;
  int e0 = off[v], e1 = off[v + 1];
  for (int s = e0 + ln; s < e1; s += 64) {
    int u = adj[s];
    lg += logf(s1v + LAMC * (S2[u] - pad));
  }
#pragma unroll
  for (int m = 1; m < 64; m <<= 1) {
    d += __shfl_xor(d, m, 64);
    lg += __shfl_xor(lg, m, 64);
  }
  if (ln == 0) {
    float inv = idi[v];
    float posv = d * inv * TEMP_INV;
    float negv = lg * inv;
    atomicAdd(out, (negv - posv) * (1.0f / (float)N));
  }
}

// ---------------- host ----------------
extern "C" void kernel_launch(void* const* d_in, const int* in_sizes, int n_in,
                              void* d_out, int out_size, void* d_ws, size_t ws_size,
                              hipStream_t stream) {
  const float* feat  = (const float*)d_in[0];
  const float* W1    = (const float*)d_in[1];
  const float* b1    = (const float*)d_in[2];
  const float* W2    = (const float*)d_in[3];
  const float* b2    = (const float*)d_in[4];
  const float* Wt1   = (const float*)d_in[5];
  const float* bt1   = (const float*)d_in[6];
  const float* gamma = (const float*)d_in[7];
  const float* beta  = (const float*)d_in[8];
  const float* Wt2   = (const float*)d_in[9];
  const float* bt2   = (const float*)d_in[10];
  const float* Wp    = (const float*)d_in[11];
  const float* bp    = (const float*)d_in[12];
  const int*   src   = (const int*)d_in[13];
  const int*   dst   = (const int*)d_in[14];
  const int N = in_sizes[0] / 512;
  const int E = in_sizes[13];
  const int NTI = (N + 255) / 256, NPAD = NTI * 256, JT = NPAD / 32;
  const int JS = 25;  // grid 40x25 = 1000 blocks ~= 3.9/CU, smooth tail
  const float PADF = (float)(NPAD - N);

  char* p = (char*)d_ws;
  auto alloc = [&](size_t bytes) { char* r = p; p += (bytes + 255) & ~(size_t)255; return r; };
  float* B0 = (float*)alloc((size_t)N * 256 * 4);            // xw1 -> xw2 -> zsum
  float* B1 = (float*)alloc((size_t)N * 256 * 4);            // t -> tr -> trans -> p -> q
  float* B2 = (float*)alloc((size_t)N * 256 * 4);            // h1 -> h2 -> z
  unsigned short* zb = (unsigned short*)alloc((size_t)NPAD * 256 * 2);
  unsigned short* qb = (unsigned short*)alloc((size_t)NPAD * 256 * 2);
  int*   off = (int*)alloc((size_t)(N + 1) * 4);
  int*   adj = (int*)alloc((size_t)E * 4);
  float* aw  = (float*)alloc((size_t)E * 4);
  char*  zblk = p;                                           // region zeroed each launch
  float* deg_out = (float*)alloc((size_t)N * 4);
  float* deg_in  = (float*)alloc((size_t)N * 4);
  int*   cur     = (int*)alloc((size_t)N * 4);
  float* S1 = (float*)alloc((size_t)N * 4);
  float* S2 = (float*)alloc((size_t)N * 4);
  float* bns  = (float*)alloc(256 * 4);
  float* bnss = (float*)alloc(256 * 4);
  size_t zbytes = (size_t)(p - zblk);
  float* rdo = (float*)alloc((size_t)N * 4);
  float* rdi = (float*)alloc((size_t)N * 4);
  float* idi = (float*)alloc((size_t)N * 4);
  (void)ws_size; (void)n_in; (void)out_size;

  hipMemsetAsync(zblk, 0, zbytes, stream);
  hipMemsetAsync(d_out, 0, 4, stream);

  int gE = (E + 255) / 256, gN = (N + 255) / 256, gb = (N + 31) / 32, gw = (N + 3) / 4;
  k_deg<<<gE, 256, 0, stream>>>(src, dst, deg_out, deg_in, E);
  k_rdeg<<<gN, 256, 0, stream>>>(deg_out, deg_in, rdo, rdi, idi, N);
  k_scan<<<1, 1024, 0, stream>>>(deg_in, off, N, E);
  k_fill<<<gE, 256, 0, stream>>>(src, dst, off, cur, rdo, rdi, adj, aw, E);

  // fused: xw1 = feat@W1 ; t = feat@Wt1 + bt1
  k_gemm2G<<<gb, 256, 0, stream>>>(feat, W1, Wt1, bt1, B0, B1, N);
  k_bnstat<<<(N + 63) / 64, 256, 0, stream>>>(B1, bns, bnss, N);
  k_bnrelu<<<N, 256, 0, stream>>>(B1, bns, bnss, gamma, beta, N);          // tr (in place)
  k_gemmG<256, true ><<<gb, 256, 0, stream>>>(B1, Wt2, bt2, B1, N);        // trans (in place)
  k_gemmG<256, true ><<<gb, 256, 0, stream>>>(B1, Wp, bp, B1, N);          // p (in place)

  k_agg<false, true ><<<gw, 256, 0, stream>>>(B0, off, adj, aw, b1, B2, N);  // h1
  k_gemmG<256, false><<<gb, 256, 0, stream>>>(B2, W2, nullptr, B0, N);       // xw2
  k_agg<false, false><<<gw, 256, 0, stream>>>(B0, off, adj, aw, b2, B2, N);  // h2

  int gnp = (NPAD + 3) / 4;
  k_norm<<<gnp, 256, 0, stream>>>(B2, zb, N, NPAD);  // z (in place) + zb
  k_norm<<<gnp, 256, 0, stream>>>(B1, qb, N, NPAD);  // q (in place) + qb

  dim3 gs(NTI, JS);
  k_sim<<<gs, 256, 0, stream>>>(zb, qb, S1, S2, N, JT, JS);

  k_agg<true, false><<<gw, 256, 0, stream>>>(B2, off, adj, aw, nullptr, B0, N);  // zsum
  k_final<<<gw, 256, 0, stream>>>(B0, B1, S1, S2, off, adj, idi, (float*)d_out, N, PADF);
}

// Round 5
// 813.994 us; speedup vs baseline: 1.7667x; 1.7667x over previous
//
#include <hip/hip_runtime.h>
#include <stdint.h>

// GraphECL loss on MI355X. N=10000, E=330000, IN=512, HID=OUT=256.
// TEMP=0.5, LAM=1e-3, LAMBDA_LOSS=1, BN_EPS=1e-5.

#define TEMP_INV 2.0f
#define LAMC 1.0e-3f
// sqrt(log2(e)/TEMP): folded into bf16 z/q so MFMA acc == exp2 argument
#define SSCALE 1.6986436f

typedef __attribute__((ext_vector_type(8))) __bf16 bf16x8;
typedef __attribute__((ext_vector_type(4))) float f32x4;

__device__ __forceinline__ unsigned short f2bf(float x) {
  union { float f; unsigned int u; } v; v.f = x;
  unsigned int r = v.u + 0x7FFFu + ((v.u >> 16) & 1u);
  return (unsigned short)(r >> 16);
}

__device__ __forceinline__ void g2lds16(const void* gc, void* l) {
  void* g = const_cast<void*>(gc);
  __builtin_amdgcn_global_load_lds(
      (__attribute__((address_space(1))) void*)g,
      (__attribute__((address_space(3))) void*)l, 16, 0, 0);
}

// ---------------- degrees ----------------
__global__ void k_deg(const int* __restrict__ src, const int* __restrict__ dst,
                      float* deg_out, float* deg_in, int E) {
  int i = blockIdx.x * blockDim.x + threadIdx.x;
  if (i < E) {
    atomicAdd(&deg_out[src[i]], 1.0f);
    atomicAdd(&deg_in[dst[i]], 1.0f);
  }
}

__global__ void k_rdeg(const float* __restrict__ deg_out, const float* __restrict__ deg_in,
                       float* rdo, float* rdi, float* idi, int N) {
  int i = blockIdx.x * blockDim.x + threadIdx.x;
  if (i < N) {
    float o = deg_out[i], d = deg_in[i];
    rdo[i] = rsqrtf(o);
    rdi[i] = rsqrtf(d);
    idi[i] = 1.0f / d;  // self loops guarantee d >= 1
  }
}

// exclusive prefix sum of deg_in (ints stored as exact floats); 1 block, 1024 thr
__global__ void k_scan(const float* __restrict__ deg, int* __restrict__ off, int N, int E) {
  __shared__ int sm[1024];
  int tid = threadIdx.x;
  int chunk = (N + 1023) / 1024;
  int b = tid * chunk;
  int sum = 0;
  for (int j = 0; j < chunk; j++) { int i = b + j; if (i < N) sum += (int)deg[i]; }
  sm[tid] = sum;
  __syncthreads();
  for (int s = 1; s < 1024; s <<= 1) {
    int v = (tid >= s) ? sm[tid - s] : 0;
    __syncthreads();
    sm[tid] += v;
    __syncthreads();
  }
  int run = (tid == 0) ? 0 : sm[tid - 1];
  for (int j = 0; j < chunk; j++) {
    int i = b + j;
    if (i < N) { off[i] = run; run += (int)deg[i]; }
  }
  if (tid == 0) off[N] = E;
}

__global__ void k_fill(const int* __restrict__ src, const int* __restrict__ dst,
                       const int* __restrict__ off, int* cur,
                       const float* __restrict__ rdo, const float* __restrict__ rdi,
                       int* adj, float* aw, int E) {
  int e = blockIdx.x * blockDim.x + threadIdx.x;
  if (e < E) {
    int u = src[e], v = dst[e];
    int slot = off[v] + atomicAdd(&cur[v], 1);
    adj[slot] = u;
    aw[slot] = rdo[u] * rdi[v];  // symmetric GCN norm per edge
  }
}

// ------- fp32 GEMM: C[M,256] = A[M,K] @ W[K,256] (+bias) -------
// BM=32 -> 313 blocks (all CUs covered). 256 thr, thread = 2 rows x 16 cols
// (cols 64t+4cg). W tiles (32x256 fp32 = 32KB) double-buffered in LDS via
// global_load_lds; STAGE(t+1) issued before COMPUTE(t) so staging latency
// hides under ~2048 cy of FMA (the pattern that fixed k_sim). A rows read
// per-lane from global (L3-resident). acc is only 2x16 floats -> no spill
// (round-4 lesson: 4x16-per-matrix acc arrays spilled, VGPR=60, 7% VALU).
// In-place (C==A) safe: each thread reads only its own 2 rows, stores at end.
template <int K, bool BIAS>
__global__ __launch_bounds__(256, 2) void k_gemmL(const float* A,
                                                  const float* __restrict__ W,
                                                  const float* __restrict__ bias,
                                                  float* C, int M) {
  __shared__ __align__(1024) float Wl[2][32][256];
  const int tid = threadIdx.x;
  const int wv = tid >> 6, ln = tid & 63;
  const int rg = tid >> 4, cg = tid & 15;
  const int row0 = blockIdx.x * 32 + rg * 2;
  const int cb = cg * 4;
  int r0 = row0 < M ? row0 : M - 1;
  int r1 = row0 + 1 < M ? row0 + 1 : M - 1;
  const float* Ar0 = A + (size_t)r0 * K;
  const float* Ar1 = A + (size_t)r1 * K;

  auto STAGE = [&](int k0, int b) {
#pragma unroll
    for (int it = 0; it < 8; it++) {
      int r = it * 4 + wv;                 // 4 rows per it across the 4 waves
      const float* g = W + (size_t)(k0 + r) * 256 + ln * 4;  // lane covers 1KB row
      g2lds16(g, (char*)&Wl[b][r][0] + ln * 16);
    }
  };

  constexpr int NC = K / 32;
  STAGE(0, 0);
  float acc[2][16] = {};
  for (int t = 0; t < NC; t++) {
    __syncthreads();                        // Wl[t&1] staged (vmcnt drained)
    if (t + 1 < NC) STAGE((t + 1) * 32, (t + 1) & 1);
    const float* Wc = &Wl[t & 1][0][0];
    const int k0 = t * 32;
#pragma unroll
    for (int k4 = 0; k4 < 32; k4 += 4) {
      float4 a0 = *(const float4*)(Ar0 + k0 + k4);
      float4 a1 = *(const float4*)(Ar1 + k0 + k4);
      float a0v[4] = {a0.x, a0.y, a0.z, a0.w};
      float a1v[4] = {a1.x, a1.y, a1.z, a1.w};
#pragma unroll
      for (int i = 0; i < 4; i++) {
#pragma unroll
        for (int tt = 0; tt < 4; tt++) {
          float4 w4 = *(const float4*)(Wc + (k4 + i) * 256 + 64 * tt + cb);
          acc[0][4 * tt + 0] += a0v[i] * w4.x; acc[0][4 * tt + 1] += a0v[i] * w4.y;
          acc[0][4 * tt + 2] += a0v[i] * w4.z; acc[0][4 * tt + 3] += a0v[i] * w4.w;
          acc[1][4 * tt + 0] += a1v[i] * w4.x; acc[1][4 * tt + 1] += a1v[i] * w4.y;
          acc[1][4 * tt + 2] += a1v[i] * w4.z; acc[1][4 * tt + 3] += a1v[i] * w4.w;
        }
      }
    }
  }
#pragma unroll
  for (int r = 0; r < 2; r++) {
    int rr = row0 + r;
    if (rr < M) {
      float* crow = C + (size_t)rr * 256;
#pragma unroll
      for (int tt = 0; tt < 4; tt++) {
        int c = 64 * tt + cb;
        float4 v = {acc[r][4 * tt], acc[r][4 * tt + 1], acc[r][4 * tt + 2], acc[r][4 * tt + 3]};
        if constexpr (BIAS) {
          float4 b4 = *(const float4*)(bias + c);
          v.x += b4.x; v.y += b4.y; v.z += b4.z; v.w += b4.w;
        }
        *(float4*)(crow + c) = v;
      }
    }
  }
}

// ---------------- BatchNorm (train) stats + apply + relu ----------------
__global__ void k_bnstat(const float* __restrict__ T, float* s, float* ss, int M) {
  int c = threadIdx.x;
  int r0 = blockIdx.x * 64;
  float a = 0, b = 0;
  for (int r = r0; r < r0 + 64 && r < M; r++) {
    float v = T[(size_t)r * 256 + c];
    a += v; b += v * v;
  }
  atomicAdd(&s[c], a);
  atomicAdd(&ss[c], b);
}

__global__ void k_bnrelu(float* T, const float* __restrict__ s, const float* __restrict__ ss,
                         const float* __restrict__ g, const float* __restrict__ b, int M) {
  int r = blockIdx.x, c = threadIdx.x;
  float invM = 1.0f / (float)M;
  float mu = s[c] * invM;
  float var = ss[c] * invM - mu * mu;   // biased var, matches jnp.var
  float w = rsqrtf(var + 1e-5f) * g[c];
  float v = T[(size_t)r * 256 + c];
  v = (v - mu) * w + b[c];
  T[(size_t)r * 256 + c] = fmaxf(v, 0.0f);
}

// ---------------- CSR gather-aggregate: Y[v] = sum_{in-edges} w * X[src] (+bias)(relu) ---------
template <bool UNIT, bool RELU>
__global__ __launch_bounds__(256) void k_agg(const float* __restrict__ X, const int* __restrict__ off,
                                             const int* __restrict__ adj, const float* __restrict__ w,
                                             const float* __restrict__ bias, float* __restrict__ Y, int N) {
  int wv = threadIdx.x >> 6, ln = threadIdx.x & 63;
  int v = blockIdx.x * 4 + wv;
  if (v >= N) return;
  int s0 = off[v], s1 = off[v + 1];
  const float4* X4 = (const float4*)X;
  float4 acc = {0, 0, 0, 0};
  for (int s = s0; s < s1; s++) {
    int u = adj[s];
    float wt = UNIT ? 1.0f : w[s];
    float4 x = X4[(size_t)u * 64 + ln];
    acc.x += wt * x.x; acc.y += wt * x.y; acc.z += wt * x.z; acc.w += wt * x.w;
  }
  if constexpr (!UNIT) {
    float4 b = ((const float4*)bias)[ln];
    acc.x += b.x; acc.y += b.y; acc.z += b.z; acc.w += b.w;
  }
  if constexpr (RELU) {
    acc.x = fmaxf(acc.x, 0.f); acc.y = fmaxf(acc.y, 0.f);
    acc.z = fmaxf(acc.z, 0.f); acc.w = fmaxf(acc.w, 0.f);
  }
  ((float4*)Y)[(size_t)v * 64 + ln] = acc;
}

// ---------------- row L2-normalize (in place) + scaled bf16 copy; zero pad rows -----------
__global__ __launch_bounds__(256) void k_norm(float* X, unsigned short* Xb, int N, int NPAD) {
  int wv = threadIdx.x >> 6, ln = threadIdx.x & 63;
  int r = blockIdx.x * 4 + wv;
  if (r >= NPAD) return;
  if (r >= N) {  // exact zeros -> each pad j-row adds exp2(0)=1, corrected in k_final
    ushort4 z = {0, 0, 0, 0};
    ((ushort4*)Xb)[(size_t)r * 64 + ln] = z;
    return;
  }
  float4 x = ((const float4*)X)[(size_t)r * 64 + ln];
  float ss = x.x * x.x + x.y * x.y + x.z * x.z + x.w * x.w;
#pragma unroll
  for (int m = 1; m < 64; m <<= 1) ss += __shfl_xor(ss, m, 64);
  float sc = 1.0f / fmaxf(sqrtf(ss), 1e-12f);
  float4 xn = {x.x * sc, x.y * sc, x.z * sc, x.w * sc};
  ((float4*)X)[(size_t)r * 64 + ln] = xn;
  float bs = sc * SSCALE;
  ushort4 b;
  b.x = f2bf(x.x * bs); b.y = f2bf(x.y * bs);
  b.z = f2bf(x.z * bs); b.w = f2bf(x.w * bs);
  ((ushort4*)Xb)[(size_t)r * 64 + ln] = b;
}

// ---------------- similarity row-sums: S1[i]=sum_j exp(z_i.z_j/T), S2[i]=sum_j exp(z_i.q_j/T) ---
// 256 i-rows/block (4 waves x 64 rows, rf=4 -> 64 FLOP per LDS byte), A-frags
// loaded per-lane from global (once per block). j-tiles of 32 Z + 32 Q rows,
// double-buffered in LDS (2 x 32 KB); STAGE(t+1) issued BEFORE COMPUTE(t) so
// L2/L3 staging latency hides under ~2500 cy of MFMA (T3-minimum pipeline,
// one barrier per tile). XOR swizzle byte^=((row&7)<<4) on global source +
// ds_read address (linear LDS dest), bank-group uniform for all reads.
__global__ __launch_bounds__(256, 2) void k_sim(const unsigned short* __restrict__ Zb,
                                                const unsigned short* __restrict__ Qb,
                                                float* __restrict__ S1, float* __restrict__ S2,
                                                int N, int JT, int JS) {
  __shared__ __align__(1024) char LB[2][32768];
  const int tid = threadIdx.x;
  const int wv = tid >> 6, ln = tid & 63;
  const int i0 = blockIdx.x * 256;
  const int wb = wv * 64;

  auto STAGE = [&](int jt, int b) {
    int j0 = jt * 32;
    char* Lb = (char*)LB[b];
#pragma unroll
    for (int it = 0; it < 8; it++) {
      int c = it * 4 + wv;                 // 1KB chunk = 2 rows
      int L = c * 1024 + ln * 16;
      int r = L >> 9;                      // 0..31 = Z rows, 32..63 = Q rows
      int o = (L & 511) ^ ((r & 7) << 4);
      const char* g = (r < 32) ? (const char*)Zb + (size_t)(j0 + r) * 512 + o
                               : (const char*)Qb + (size_t)(j0 + r - 32) * 512 + o;
      g2lds16(g, Lb + c * 1024);
    }
  };

  int jt0 = (blockIdx.y * JT) / JS;
  int jt1 = ((blockIdx.y + 1) * JT) / JS;

  STAGE(jt0, 0);

  // A fragments from global: wave owns rows i0+wb .. +63 (4 rowfrags), K=256
  bf16x8 af[4][8];
#pragma unroll
  for (int rf = 0; rf < 4; rf++) {
    const char* arow = (const char*)(Zb + (size_t)(i0 + wb + rf * 16 + (ln & 15)) * 256);
#pragma unroll
    for (int kk = 0; kk < 8; kk++)
      af[rf][kk] = *(const bf16x8*)(arow + kk * 64 + ((ln >> 4) << 4));
  }

  f32x4 rs[4][2] = {};  // per-lane row-sum accumulators [rowfrag][mat]

  __syncthreads();      // tile jt0 staged (vmcnt drained at barrier)
  int cur = 0;
  for (int jt = jt0; jt < jt1; jt++) {
    if (jt + 1 < jt1) STAGE(jt + 1, cur ^ 1);   // prefetch overlaps compute
    const char* Lb = (const char*)LB[cur];
#pragma unroll
    for (int m = 0; m < 2; m++) {
      f32x4 acc[4][2] = {};
#pragma unroll
      for (int kk = 0; kk < 8; kk++) {
#pragma unroll
        for (int cf = 0; cf < 2; cf++) {
          int brow = m * 32 + cf * 16 + (ln & 15);
          int o = (kk * 64 + ((ln >> 4) << 4)) ^ ((brow & 7) << 4);
          bf16x8 bb = *(const bf16x8*)(Lb + brow * 512 + o);
#pragma unroll
          for (int rf = 0; rf < 4; rf++)
            acc[rf][cf] = __builtin_amdgcn_mfma_f32_16x16x32_bf16(af[rf][kk], bb, acc[rf][cf], 0, 0, 0);
        }
      }
#pragma unroll
      for (int rf = 0; rf < 4; rf++)
#pragma unroll
        for (int i = 0; i < 4; i++)
          rs[rf][m][i] += exp2f(acc[rf][0][i]) + exp2f(acc[rf][1][i]);
    }
    __syncthreads();    // next tile staged; this tile fully consumed
    cur ^= 1;
  }

  // reduce the 16 lanes (same ln>>4 group) sharing each output row; row=(ln>>4)*4+i
#pragma unroll
  for (int rf = 0; rf < 4; rf++)
#pragma unroll
    for (int m = 0; m < 2; m++)
#pragma unroll
      for (int i = 0; i < 4; i++) {
        float v = rs[rf][m][i];
        v += __shfl_xor(v, 1, 64);
        v += __shfl_xor(v, 2, 64);
        v += __shfl_xor(v, 4, 64);
        v += __shfl_xor(v, 8, 64);
        if ((ln & 15) == 0) {
          int row = i0 + wb + rf * 16 + ((ln >> 4) << 2) + i;
          if (row < N) atomicAdd(((m == 0) ? S1 : S2) + row, v);
        }
      }
}

// ---------------- final loss ----------------
__global__ __launch_bounds__(256) void k_final(const float* __restrict__ zsum, const float* __restrict__ q,
                                               const float* __restrict__ S1, const float* __restrict__ S2,
                                               const int* __restrict__ off, const int* __restrict__ adj,
                                               const float* __restrict__ idi, float* __restrict__ out,
                                               int N, float pad) {
  int wv = threadIdx.x >> 6, ln = threadIdx.x & 63;
  int v = blockIdx.x * 4 + wv;
  if (v >= N) return;
  float4 zs = ((const float4*)zsum)[(size_t)v * 64 + ln];
  float4 qv = ((const float4*)q)[(size_t)v * 64 + ln];
  float d = zs.x * qv.x + zs.y * qv.y + zs.z * qv.z + zs.w * qv.w;
  float s1v = S1[v] - pad;  // remove pad-row exp2(0)=1 contributions
  float lg = 0.0f;
  int e0 = off[v], e1 = off[v + 1];
  for (int s = e0 + ln; s < e1; s += 64) {
    int u = adj[s];
    lg += logf(s1v + LAMC * (S2[u] - pad));
  }
#pragma unroll
  for (int m = 1; m < 64; m <<= 1) {
    d += __shfl_xor(d, m, 64);
    lg += __shfl_xor(lg, m, 64);
  }
  if (ln == 0) {
    float inv = idi[v];
    float posv = d * inv * TEMP_INV;
    float negv = lg * inv;
    atomicAdd(out, (negv - posv) * (1.0f / (float)N));
  }
}

// ---------------- host ----------------
extern "C" void kernel_launch(void* const* d_in, const int* in_sizes, int n_in,
                              void* d_out, int out_size, void* d_ws, size_t ws_size,
                              hipStream_t stream) {
  const float* feat  = (const float*)d_in[0];
  const float* W1    = (const float*)d_in[1];
  const float* b1    = (const float*)d_in[2];
  const float* W2    = (const float*)d_in[3];
  const float* b2    = (const float*)d_in[4];
  const float* Wt1   = (const float*)d_in[5];
  const float* bt1   = (const float*)d_in[6];
  const float* gamma = (const float*)d_in[7];
  const float* beta  = (const float*)d_in[8];
  const float* Wt2   = (const float*)d_in[9];
  const float* bt2   = (const float*)d_in[10];
  const float* Wp    = (const float*)d_in[11];
  const float* bp    = (const float*)d_in[12];
  const int*   src   = (const int*)d_in[13];
  const int*   dst   = (const int*)d_in[14];
  const int N = in_sizes[0] / 512;
  const int E = in_sizes[13];
  const int NTI = (N + 255) / 256, NPAD = NTI * 256, JT = NPAD / 32;
  const int JS = 25;  // grid 40x25 = 1000 blocks ~= 3.9/CU, smooth tail
  const float PADF = (float)(NPAD - N);

  char* p = (char*)d_ws;
  auto alloc = [&](size_t bytes) { char* r = p; p += (bytes + 255) & ~(size_t)255; return r; };
  float* B0 = (float*)alloc((size_t)N * 256 * 4);            // xw1 -> xw2 -> zsum
  float* B1 = (float*)alloc((size_t)N * 256 * 4);            // t -> tr -> trans -> p -> q
  float* B2 = (float*)alloc((size_t)N * 256 * 4);            // h1 -> h2 -> z
  unsigned short* zb = (unsigned short*)alloc((size_t)NPAD * 256 * 2);
  unsigned short* qb = (unsigned short*)alloc((size_t)NPAD * 256 * 2);
  int*   off = (int*)alloc((size_t)(N + 1) * 4);
  int*   adj = (int*)alloc((size_t)E * 4);
  float* aw  = (float*)alloc((size_t)E * 4);
  char*  zblk = p;                                           // region zeroed each launch
  float* deg_out = (float*)alloc((size_t)N * 4);
  float* deg_in  = (float*)alloc((size_t)N * 4);
  int*   cur     = (int*)alloc((size_t)N * 4);
  float* S1 = (float*)alloc((size_t)N * 4);
  float* S2 = (float*)alloc((size_t)N * 4);
  float* bns  = (float*)alloc(256 * 4);
  float* bnss = (float*)alloc(256 * 4);
  size_t zbytes = (size_t)(p - zblk);
  float* rdo = (float*)alloc((size_t)N * 4);
  float* rdi = (float*)alloc((size_t)N * 4);
  float* idi = (float*)alloc((size_t)N * 4);
  (void)ws_size; (void)n_in; (void)out_size;

  hipMemsetAsync(zblk, 0, zbytes, stream);
  hipMemsetAsync(d_out, 0, 4, stream);

  int gE = (E + 255) / 256, gN = (N + 255) / 256, gb = (N + 31) / 32, gw = (N + 3) / 4;
  k_deg<<<gE, 256, 0, stream>>>(src, dst, deg_out, deg_in, E);
  k_rdeg<<<gN, 256, 0, stream>>>(deg_out, deg_in, rdo, rdi, idi, N);
  k_scan<<<1, 1024, 0, stream>>>(deg_in, off, N, E);
  k_fill<<<gE, 256, 0, stream>>>(src, dst, off, cur, rdo, rdi, adj, aw, E);

  k_gemmL<512, false><<<gb, 256, 0, stream>>>(feat, W1, nullptr, B0, N);   // xw1
  k_gemmL<512, true ><<<gb, 256, 0, stream>>>(feat, Wt1, bt1, B1, N);      // t
  k_bnstat<<<(N + 63) / 64, 256, 0, stream>>>(B1, bns, bnss, N);
  k_bnrelu<<<N, 256, 0, stream>>>(B1, bns, bnss, gamma, beta, N);          // tr (in place)
  k_gemmL<256, true ><<<gb, 256, 0, stream>>>(B1, Wt2, bt2, B1, N);        // trans (in place)
  k_gemmL<256, true ><<<gb, 256, 0, stream>>>(B1, Wp, bp, B1, N);          // p (in place)

  k_agg<false, true ><<<gw, 256, 0, stream>>>(B0, off, adj, aw, b1, B2, N);  // h1
  k_gemmL<256, false><<<gb, 256, 0, stream>>>(B2, W2, nullptr, B0, N);       // xw2
  k_agg<false, false><<<gw, 256, 0, stream>>>(B0, off, adj, aw, b2, B2, N);  // h2

  int gnp = (NPAD + 3) / 4;
  k_norm<<<gnp, 256, 0, stream>>>(B2, zb, N, NPAD);  // z (in place) + zb
  k_norm<<<gnp, 256, 0, stream>>>(B1, qb, N, NPAD);  // q (in place) + qb

  dim3 gs(NTI, JS);
  k_sim<<<gs, 256, 0, stream>>>(zb, qb, S1, S2, N, JT, JS);

  k_agg<true, false><<<gw, 256, 0, stream>>>(B2, off, adj, aw, nullptr, B0, N);  // zsum
  k_final<<<gw, 256, 0, stream>>>(B0, B1, S1, S2, off, adj, idi, (float*)d_out, N, PADF);
}

// Round 7
// 781.603 us; speedup vs baseline: 1.8399x; 1.0414x over previous
//
#include <hip/hip_runtime.h>
#include <stdint.h>

// GraphECL loss on MI355X. N=10000, E=330000, IN=512, HID=OUT=256.
// TEMP=0.5, LAM=1e-3, LAMBDA_LOSS=1, BN_EPS=1e-5.

#define TEMP_INV 2.0f
#define LAMC 1.0e-3f
// sqrt(log2(e)/TEMP): folded into bf16 z/q so MFMA acc == exp2 argument
#define SSCALE 1.6986436f

typedef __attribute__((ext_vector_type(8))) __bf16 bf16x8;
typedef __attribute__((ext_vector_type(8))) unsigned short u16x8;
typedef __attribute__((ext_vector_type(4))) float f32x4;

__device__ __forceinline__ unsigned short f2bf(float x) {
  union { float f; unsigned int u; } v; v.f = x;
  unsigned int r = v.u + 0x7FFFu + ((v.u >> 16) & 1u);
  return (unsigned short)(r >> 16);
}
__device__ __forceinline__ float bf2f(unsigned short h) {
  union { unsigned int u; float f; } v; v.u = ((unsigned int)h) << 16; return v.f;
}

__device__ __forceinline__ void g2lds16(const void* gc, void* l) {
  void* g = const_cast<void*>(gc);
  __builtin_amdgcn_global_load_lds(
      (__attribute__((address_space(1))) void*)g,
      (__attribute__((address_space(3))) void*)l, 16, 0, 0);
}

// ---------------- degrees / CSR build ----------------
__global__ void k_deg(const int* __restrict__ src, const int* __restrict__ dst,
                      float* deg_out, float* deg_in, int E) {
  int i = blockIdx.x * blockDim.x + threadIdx.x;
  if (i < E) {
    atomicAdd(&deg_out[src[i]], 1.0f);
    atomicAdd(&deg_in[dst[i]], 1.0f);
  }
}

__global__ void k_rdeg(const float* __restrict__ deg_out, const float* __restrict__ deg_in,
                       float* rdo, float* rdi, float* idi, int N) {
  int i = blockIdx.x * blockDim.x + threadIdx.x;
  if (i < N) {
    float o = deg_out[i], d = deg_in[i];
    rdo[i] = rsqrtf(o);
    rdi[i] = rsqrtf(d);
    idi[i] = 1.0f / d;  // self loops guarantee d >= 1
  }
}

__global__ void k_scan(const float* __restrict__ deg, int* __restrict__ off, int N, int E) {
  __shared__ int sm[1024];
  int tid = threadIdx.x;
  int chunk = (N + 1023) / 1024;
  int b = tid * chunk;
  int sum = 0;
  for (int j = 0; j < chunk; j++) { int i = b + j; if (i < N) sum += (int)deg[i]; }
  sm[tid] = sum;
  __syncthreads();
  for (int s = 1; s < 1024; s <<= 1) {
    int v = (tid >= s) ? sm[tid - s] : 0;
    __syncthreads();
    sm[tid] += v;
    __syncthreads();
  }
  int run = (tid == 0) ? 0 : sm[tid - 1];
  for (int j = 0; j < chunk; j++) {
    int i = b + j;
    if (i < N) { off[i] = run; run += (int)deg[i]; }
  }
  if (tid == 0) off[N] = E;
}

__global__ void k_fill(const int* __restrict__ src, const int* __restrict__ dst,
                       const int* __restrict__ off, int* cur,
                       const float* __restrict__ rdo, const float* __restrict__ rdi,
                       int* adj, float* aw, int E) {
  int e = blockIdx.x * blockDim.x + threadIdx.x;
  if (e < E) {
    int u = src[e], v = dst[e];
    int slot = off[v] + atomicAdd(&cur[v], 1);
    adj[slot] = u;
    aw[slot] = rdo[u] * rdi[v];
  }
}

// W[K,256] fp32 -> W^T[256,K] bf16 hi/lo (0.5MB scratch, launched 4x)
__global__ void k_cvtWt(const float* __restrict__ W, unsigned short* __restrict__ Wth,
                        unsigned short* __restrict__ Wtl, int K) {
  int k = blockIdx.x, c = threadIdx.x;
  float x = W[(size_t)k * 256 + c];
  unsigned short h = f2bf(x);
  Wth[(size_t)c * K + k] = h;
  Wtl[(size_t)c * K + k] = f2bf(x - bf2f(h));
}

// ---------------- split-bf16 MFMA GEMM: C[M,256] = A@W (+bias), A fp32 ----------------
// C = Ah@Wh + Ah@Wl + Al@Wh (fp32 acc, ~6e-5 rel err). A hi/lo split IN-KERNEL
// (no bf16 A scratch -> ws stays ~48MB; round-6 lesson: +32MB scratch overflowed
// d_ws -> GPU fault). BM=32, 4 waves = 2 rowgroups x 2 colhalves; wave = 16 rows
// x 128 cols (8 j-frags, acc 32 VGPR). W^T k-chunk tiles (2mat x 4kslot x 256col
// x 16B = 32KB) double-buffered via global_load_lds, STAGE(t+1)+A(t+1) prefetch
// before COMPUTE(t), 1 barrier/chunk (k_sim's proven flow). In-place (C==A)
// safe: block touches only its own 32 A-rows; the loop's final __syncthreads()
// is after every wave's last A-read, C stored after.
template <int K, bool BIAS>
__global__ __launch_bounds__(256, 2) void k_gemmM(
    const float* A,
    const unsigned short* __restrict__ Wth, const unsigned short* __restrict__ Wtl,
    const float* __restrict__ bias, float* C, int M) {
  __shared__ __align__(1024) char LB[2][32768];
  const int tid = threadIdx.x, wv = tid >> 6, ln = tid & 63;
  const int rg = wv & 1, ch = wv >> 1;
  const int i0 = blockIdx.x * 32;
  int arow = i0 + rg * 16 + (ln & 15);
  if (arow >= M) arow = M - 1;           // clamp (dead rows never stored)
  const int kg = ln >> 4;
  const float* Ar = A + (size_t)arow * K + kg * 8;

  auto STAGE = [&](int kc, int b) {
#pragma unroll
    for (int it = 0; it < 8; it++) {
      int idx = it * 4 + wv;
      int mat = idx >> 4, s = (idx >> 2) & 3, cb = idx & 3;
      const unsigned short* Wt = mat ? Wtl : Wth;
      const char* src = (const char*)(Wt + (size_t)(cb * 64 + ln) * K) + kc * 64 + s * 16;
      g2lds16(src, (char*)LB[b] + mat * 16384 + s * 4096 + cb * 1024);
    }
  };

  auto LOADA = [&](int t, bf16x8& ah, bf16x8& al) {
    float4 x0 = *(const float4*)(Ar + t * 32);
    float4 x1 = *(const float4*)(Ar + t * 32 + 4);
    float xs[8] = {x0.x, x0.y, x0.z, x0.w, x1.x, x1.y, x1.z, x1.w};
    union { u16x8 u; bf16x8 b; } hu, lu;
#pragma unroll
    for (int j = 0; j < 8; j++) {
      unsigned short h = f2bf(xs[j]);
      hu.u[j] = h;
      lu.u[j] = f2bf(xs[j] - bf2f(h));   // residual exact (Sterbenz), then bf16
    }
    ah = hu.b; al = lu.b;
  };

  constexpr int NC = K / 32;
  STAGE(0, 0);
  bf16x8 ah, al;
  LOADA(0, ah, al);
  f32x4 acc[8] = {};
  int b = 0;
  __syncthreads();
  for (int t = 0; t < NC; t++) {
    bf16x8 ah_n = ah, al_n = al;
    if (t + 1 < NC) {
      STAGE(t + 1, b ^ 1);
      LOADA(t + 1, ah_n, al_n);
    }
    const char* Lb = (const char*)LB[b];
    __builtin_amdgcn_s_setprio(1);
#pragma unroll
    for (int jf = 0; jf < 8; jf++) {
      int col = ch * 128 + jf * 16 + (ln & 15);
      bf16x8 bh = *(const bf16x8*)(Lb + kg * 4096 + col * 16);
      bf16x8 bl = *(const bf16x8*)(Lb + 16384 + kg * 4096 + col * 16);
      acc[jf] = __builtin_amdgcn_mfma_f32_16x16x32_bf16(ah, bh, acc[jf], 0, 0, 0);
      acc[jf] = __builtin_amdgcn_mfma_f32_16x16x32_bf16(al, bh, acc[jf], 0, 0, 0);
      acc[jf] = __builtin_amdgcn_mfma_f32_16x16x32_bf16(ah, bl, acc[jf], 0, 0, 0);
    }
    __builtin_amdgcn_s_setprio(0);
    __syncthreads();   // prefetch landed (vmcnt drain) + LB[b] fully consumed
    b ^= 1; ah = ah_n; al = al_n;
  }
  // C/D layout: col = ln&15, row = (ln>>4)*4 + i  [m89 verified]
#pragma unroll
  for (int i = 0; i < 4; i++) {
    int row = i0 + rg * 16 + kg * 4 + i;
    if (row < M) {
#pragma unroll
      for (int jf = 0; jf < 8; jf++) {
        int col = ch * 128 + jf * 16 + (ln & 15);
        float v = acc[jf][i];
        if constexpr (BIAS) v += bias[col];
        C[(size_t)row * 256 + col] = v;
      }
    }
  }
}

// ---------------- BatchNorm (train) stats + apply + relu ----------------
__global__ void k_bnstat(const float* __restrict__ T, float* s, float* ss, int M) {
  int c = threadIdx.x;
  int r0 = blockIdx.x * 64;
  float a = 0, b = 0;
  for (int r = r0; r < r0 + 64 && r < M; r++) {
    float v = T[(size_t)r * 256 + c];
    a += v; b += v * v;
  }
  atomicAdd(&s[c], a);
  atomicAdd(&ss[c], b);
}

__global__ void k_bnrelu(float* T, const float* __restrict__ s, const float* __restrict__ ss,
                         const float* __restrict__ g, const float* __restrict__ b, int M) {
  int r = blockIdx.x, c = threadIdx.x;
  float invM = 1.0f / (float)M;
  float mu = s[c] * invM;
  float var = ss[c] * invM - mu * mu;
  float w = rsqrtf(var + 1e-5f) * g[c];
  float v = T[(size_t)r * 256 + c];
  v = (v - mu) * w + b[c];
  T[(size_t)r * 256 + c] = fmaxf(v, 0.0f);
}

// ---- column-sliced CSR gather: Y[v] = sum_e w*X[src] (+bias)(relu), 64-col slices ----
// slice = slow grid index -> one 2.5MB column slice hot in L2 at a time.
template <bool UNIT, bool RELU>
__global__ __launch_bounds__(256) void k_aggS(
    const float* __restrict__ X, const int* __restrict__ off, const int* __restrict__ adj,
    const float* __restrict__ w, const float* __restrict__ bias, float* __restrict__ Y,
    int N, int NV) {
  int slice = blockIdx.x / NV, vc = blockIdx.x - slice * NV;
  int wv = threadIdx.x >> 6, ln = threadIdx.x & 63;
  int v = vc * 4 + wv;
  if (v >= N) return;
  int c = slice * 64 + ln;
  int s0 = off[v], s1 = off[v + 1];
  float acc = 0.f;
  int s = s0;
  for (; s + 3 < s1; s += 4) {
    int u0 = adj[s], u1 = adj[s + 1], u2 = adj[s + 2], u3 = adj[s + 3];
    float x0 = X[(size_t)u0 * 256 + c], x1 = X[(size_t)u1 * 256 + c];
    float x2 = X[(size_t)u2 * 256 + c], x3 = X[(size_t)u3 * 256 + c];
    if constexpr (UNIT) acc += (x0 + x1) + (x2 + x3);
    else acc += w[s] * x0 + w[s + 1] * x1 + w[s + 2] * x2 + w[s + 3] * x3;
  }
  for (; s < s1; s++) {
    float wt = UNIT ? 1.f : w[s];
    acc += wt * X[(size_t)adj[s] * 256 + c];
  }
  if constexpr (!UNIT) acc += bias[c];
  if constexpr (RELU) acc = fmaxf(acc, 0.f);
  Y[(size_t)v * 256 + c] = acc;
}

// ---------------- row L2-normalize (in place) + scaled bf16 copy; zero pad rows -----------
__global__ __launch_bounds__(256) void k_norm(float* X, unsigned short* Xb, int N, int NPAD) {
  int wv = threadIdx.x >> 6, ln = threadIdx.x & 63;
  int r = blockIdx.x * 4 + wv;
  if (r >= NPAD) return;
  if (r >= N) {
    ushort4 z = {0, 0, 0, 0};
    ((ushort4*)Xb)[(size_t)r * 64 + ln] = z;
    return;
  }
  float4 x = ((const float4*)X)[(size_t)r * 64 + ln];
  float ss = x.x * x.x + x.y * x.y + x.z * x.z + x.w * x.w;
#pragma unroll
  for (int m = 1; m < 64; m <<= 1) ss += __shfl_xor(ss, m, 64);
  float sc = 1.0f / fmaxf(sqrtf(ss), 1e-12f);
  float4 xn = {x.x * sc, x.y * sc, x.z * sc, x.w * sc};
  ((float4*)X)[(size_t)r * 64 + ln] = xn;
  float bs = sc * SSCALE;
  ushort4 b;
  b.x = f2bf(x.x * bs); b.y = f2bf(x.y * bs);
  b.z = f2bf(x.z * bs); b.w = f2bf(x.w * bs);
  ((ushort4*)Xb)[(size_t)r * 64 + ln] = b;
}

// ---------------- similarity row-sums (round-5 structure + setprio) ----------------
__global__ __launch_bounds__(256, 2) void k_sim(const unsigned short* __restrict__ Zb,
                                                const unsigned short* __restrict__ Qb,
                                                float* __restrict__ S1, float* __restrict__ S2,
                                                int N, int JT, int JS) {
  __shared__ __align__(1024) char LB[2][32768];
  const int tid = threadIdx.x;
  const int wv = tid >> 6, ln = tid & 63;
  const int i0 = blockIdx.x * 256;
  const int wb = wv * 64;

  auto STAGE = [&](int jt, int b) {
    int j0 = jt * 32;
    char* Lb = (char*)LB[b];
#pragma unroll
    for (int it = 0; it < 8; it++) {
      int c = it * 4 + wv;
      int L = c * 1024 + ln * 16;
      int r = L >> 9;
      int o = (L & 511) ^ ((r & 7) << 4);
      const char* g = (r < 32) ? (const char*)Zb + (size_t)(j0 + r) * 512 + o
                               : (const char*)Qb + (size_t)(j0 + r - 32) * 512 + o;
      g2lds16(g, Lb + c * 1024);
    }
  };

  int jt0 = (blockIdx.y * JT) / JS;
  int jt1 = ((blockIdx.y + 1) * JT) / JS;

  STAGE(jt0, 0);

  bf16x8 af[4][8];
#pragma unroll
  for (int rf = 0; rf < 4; rf++) {
    const char* arow = (const char*)(Zb + (size_t)(i0 + wb + rf * 16 + (ln & 15)) * 256);
#pragma unroll
    for (int kk = 0; kk < 8; kk++)
      af[rf][kk] = *(const bf16x8*)(arow + kk * 64 + ((ln >> 4) << 4));
  }

  f32x4 rs[4][2] = {};

  __syncthreads();
  int cur = 0;
  for (int jt = jt0; jt < jt1; jt++) {
    if (jt + 1 < jt1) STAGE(jt + 1, cur ^ 1);
    const char* Lb = (const char*)LB[cur];
#pragma unroll
    for (int m = 0; m < 2; m++) {
      f32x4 acc[4][2] = {};
      __builtin_amdgcn_s_setprio(1);
#pragma unroll
      for (int kk = 0; kk < 8; kk++) {
#pragma unroll
        for (int cf = 0; cf < 2; cf++) {
          int brow = m * 32 + cf * 16 + (ln & 15);
          int o = (kk * 64 + ((ln >> 4) << 4)) ^ ((brow & 7) << 4);
          bf16x8 bb = *(const bf16x8*)(Lb + brow * 512 + o);
#pragma unroll
          for (int rf = 0; rf < 4; rf++)
            acc[rf][cf] = __builtin_amdgcn_mfma_f32_16x16x32_bf16(af[rf][kk], bb, acc[rf][cf], 0, 0, 0);
        }
      }
      __builtin_amdgcn_s_setprio(0);
#pragma unroll
      for (int rf = 0; rf < 4; rf++)
#pragma unroll
        for (int i = 0; i < 4; i++)
          rs[rf][m][i] += exp2f(acc[rf][0][i]) + exp2f(acc[rf][1][i]);
    }
    __syncthreads();
    cur ^= 1;
  }

#pragma unroll
  for (int rf = 0; rf < 4; rf++)
#pragma unroll
    for (int m = 0; m < 2; m++)
#pragma unroll
      for (int i = 0; i < 4; i++) {
        float v = rs[rf][m][i];
        v += __shfl_xor(v, 1, 64);
        v += __shfl_xor(v, 2, 64);
        v += __shfl_xor(v, 4, 64);
        v += __shfl_xor(v, 8, 64);
        if ((ln & 15) == 0) {
          int row = i0 + wb + rf * 16 + ((ln >> 4) << 2) + i;
          if (row < N) atomicAdd(((m == 0) ? S1 : S2) + row, v);
        }
      }
}

// ---------------- final loss ----------------
__global__ __launch_bounds__(256) void k_final(const float* __restrict__ zsum, const float* __restrict__ q,
                                               const float* __restrict__ S1, const float* __restrict__ S2,
                                               const int* __restrict__ off, const int* __restrict__ adj,
                                               const float* __restrict__ idi, float* __restrict__ out,
                                               int N, float pad) {
  int wv = threadIdx.x >> 6, ln = threadIdx.x & 63;
  int v = blockIdx.x * 4 + wv;
  if (v >= N) return;
  float4 zs = ((const float4*)zsum)[(size_t)v * 64 + ln];
  float4 qv = ((const float4*)q)[(size_t)v * 64 + ln];
  float d = zs.x * qv.x + zs.y * qv.y + zs.z * qv.z + zs.w * qv.w;
  float s1v = S1[v] - pad;
  float lg = 0.0f;
  int e0 = off[v], e1 = off[v + 1];
  for (int s = e0 + ln; s < e1; s += 64) {
    int u = adj[s];
    lg += logf(s1v + LAMC * (S2[u] - pad));
  }
#pragma unroll
  for (int m = 1; m < 64; m <<= 1) {
    d += __shfl_xor(d, m, 64);
    lg += __shfl_xor(lg, m, 64);
  }
  if (ln == 0) {
    float inv = idi[v];
    float posv = d * inv * TEMP_INV;
    float negv = lg * inv;
    atomicAdd(out, (negv - posv) * (1.0f / (float)N));
  }
}

// ---------------- host ----------------
extern "C" void kernel_launch(void* const* d_in, const int* in_sizes, int n_in,
                              void* d_out, int out_size, void* d_ws, size_t ws_size,
                              hipStream_t stream) {
  const float* feat  = (const float*)d_in[0];
  const float* W1    = (const float*)d_in[1];
  const float* b1    = (const float*)d_in[2];
  const float* W2    = (const float*)d_in[3];
  const float* b2    = (const float*)d_in[4];
  const float* Wt1   = (const float*)d_in[5];
  const float* bt1   = (const float*)d_in[6];
  const float* gamma = (const float*)d_in[7];
  const float* beta  = (const float*)d_in[8];
  const float* Wt2   = (const float*)d_in[9];
  const float* bt2   = (const float*)d_in[10];
  const float* Wp    = (const float*)d_in[11];
  const float* bp    = (const float*)d_in[12];
  const int*   src   = (const int*)d_in[13];
  const int*   dst   = (const int*)d_in[14];
  const int N = in_sizes[0] / 512;
  const int E = in_sizes[13];
  const int NTI = (N + 255) / 256, NPAD = NTI * 256, JT = NPAD / 32;
  const int JS = 25;
  const float PADF = (float)(NPAD - N);

  char* p = (char*)d_ws;
  auto alloc = [&](size_t bytes) { char* r = p; p += (bytes + 255) & ~(size_t)255; return r; };
  float* B0 = (float*)alloc((size_t)N * 256 * 4);            // xw1 -> xw2 -> zsum
  float* B1 = (float*)alloc((size_t)N * 256 * 4);            // t -> tr -> trans -> p -> q
  float* B2 = (float*)alloc((size_t)N * 256 * 4);            // h1 -> h2 -> z
  unsigned short* zb = (unsigned short*)alloc((size_t)NPAD * 256 * 2);
  unsigned short* qb = (unsigned short*)alloc((size_t)NPAD * 256 * 2);
  unsigned short* wth = (unsigned short*)alloc((size_t)256 * 512 * 2);
  unsigned short* wtl = (unsigned short*)alloc((size_t)256 * 512 * 2);
  int*   off = (int*)alloc((size_t)(N + 1) * 4);
  int*   adj = (int*)alloc((size_t)E * 4);
  float* aw  = (float*)alloc((size_t)E * 4);
  char*  zblk = p;                                           // zeroed each launch
  float* deg_out = (float*)alloc((size_t)N * 4);
  float* deg_in  = (float*)alloc((size_t)N * 4);
  int*   cur     = (int*)alloc((size_t)N * 4);
  float* S1 = (float*)alloc((size_t)N * 4);
  float* S2 = (float*)alloc((size_t)N * 4);
  float* bns  = (float*)alloc(256 * 4);
  float* bnss = (float*)alloc(256 * 4);
  size_t zbytes = (size_t)(p - zblk);
  float* rdo = (float*)alloc((size_t)N * 4);
  float* rdi = (float*)alloc((size_t)N * 4);
  float* idi = (float*)alloc((size_t)N * 4);
  (void)ws_size; (void)n_in; (void)out_size;

  hipMemsetAsync(zblk, 0, zbytes, stream);
  hipMemsetAsync(d_out, 0, 4, stream);

  int gE = (E + 255) / 256, gN = (N + 255) / 256;
  int NV = (N + 3) / 4, gw = NV, gm = (N + 31) / 32;
  k_deg<<<gE, 256, 0, stream>>>(src, dst, deg_out, deg_in, E);
  k_rdeg<<<gN, 256, 0, stream>>>(deg_out, deg_in, rdo, rdi, idi, N);
  k_scan<<<1, 1024, 0, stream>>>(deg_in, off, N, E);
  k_fill<<<gE, 256, 0, stream>>>(src, dst, off, cur, rdo, rdi, adj, aw, E);

  // --- encoder GEMMs via split-bf16 MFMA (A split in-kernel) ---
  k_cvtWt<<<512, 256, 0, stream>>>(W1, wth, wtl, 512);
  k_gemmM<512, false><<<gm, 256, 0, stream>>>(feat, wth, wtl, nullptr, B0, N);  // xw1
  k_cvtWt<<<512, 256, 0, stream>>>(Wt1, wth, wtl, 512);
  k_gemmM<512, true ><<<gm, 256, 0, stream>>>(feat, wth, wtl, bt1, B1, N);      // t

  k_bnstat<<<(N + 63) / 64, 256, 0, stream>>>(B1, bns, bnss, N);
  k_bnrelu<<<N, 256, 0, stream>>>(B1, bns, bnss, gamma, beta, N);               // tr

  k_cvtWt<<<256, 256, 0, stream>>>(Wt2, wth, wtl, 256);
  k_gemmM<256, true ><<<gm, 256, 0, stream>>>(B1, wth, wtl, bt2, B1, N);        // trans (in place)
  k_cvtWt<<<256, 256, 0, stream>>>(Wp, wth, wtl, 256);
  k_gemmM<256, true ><<<gm, 256, 0, stream>>>(B1, wth, wtl, bp, B1, N);         // p (in place)

  k_aggS<false, true ><<<4 * gw, 256, 0, stream>>>(B0, off, adj, aw, b1, B2, N, NV);  // h1
  k_cvtWt<<<256, 256, 0, stream>>>(W2, wth, wtl, 256);
  k_gemmM<256, false><<<gm, 256, 0, stream>>>(B2, wth, wtl, nullptr, B0, N);          // xw2
  k_aggS<false, false><<<4 * gw, 256, 0, stream>>>(B0, off, adj, aw, b2, B2, N, NV);  // h2

  int gnp = (NPAD + 3) / 4;
  k_norm<<<gnp, 256, 0, stream>>>(B2, zb, N, NPAD);  // z + zb
  k_norm<<<gnp, 256, 0, stream>>>(B1, qb, N, NPAD);  // q + qb

  dim3 gs(NTI, JS);
  k_sim<<<gs, 256, 0, stream>>>(zb, qb, S1, S2, N, JT, JS);

  k_aggS<true, false><<<4 * gw, 256, 0, stream>>>(B2, off, adj, aw, nullptr, B0, N, NV);  // zsum
  k_final<<<gw, 256, 0, stream>>>(B0, B1, S1, S2, off, adj, idi, (float*)d_out, N, PADF);
}

// Round 10
// 749.548 us; speedup vs baseline: 1.9186x; 1.0428x over previous
//
#include <hip/hip_runtime.h>
#include <stdint.h>

// GraphECL loss on MI355X. N=10000, E=330000, IN=512, HID=OUT=256.
// TEMP=0.5, LAM=1e-3, LAMBDA_LOSS=1, BN_EPS=1e-5.

#define TEMP_INV 2.0f
#define LAMC 1.0e-3f
// sqrt(1/TEMP): folded into bf16 z/q so MFMA acc == natural-log exp argument
// (consumed by __expf, the documented HIP fast intrinsic -> v_mul+v_exp_f32)
#define SSCALE 1.41421356f

typedef __attribute__((ext_vector_type(8))) __bf16 bf16x8;
typedef __attribute__((ext_vector_type(8))) unsigned short u16x8;
typedef __attribute__((ext_vector_type(4))) float f32x4;

__device__ __forceinline__ unsigned short f2bf(float x) {
  union { float f; unsigned int u; } v; v.f = x;
  unsigned int r = v.u + 0x7FFFu + ((v.u >> 16) & 1u);
  return (unsigned short)(r >> 16);
}
__device__ __forceinline__ float bf2f(unsigned short h) {
  union { unsigned int u; float f; } v; v.u = ((unsigned int)h) << 16; return v.f;
}

__device__ __forceinline__ void g2lds16(const void* gc, void* l) {
  void* g = const_cast<void*>(gc);
  __builtin_amdgcn_global_load_lds(
      (__attribute__((address_space(1))) void*)g,
      (__attribute__((address_space(3))) void*)l, 16, 0, 0);
}

// ---------------- degrees / CSR build ----------------
__global__ void k_deg(const int* __restrict__ src, const int* __restrict__ dst,
                      float* deg_out, float* deg_in, int E) {
  int i = blockIdx.x * blockDim.x + threadIdx.x;
  if (i < E) {
    atomicAdd(&deg_out[src[i]], 1.0f);
    atomicAdd(&deg_in[dst[i]], 1.0f);
  }
}

__global__ void k_rdeg(const float* __restrict__ deg_out, const float* __restrict__ deg_in,
                       float* rdo, float* rdi, float* idi, int N) {
  int i = blockIdx.x * blockDim.x + threadIdx.x;
  if (i < N) {
    float o = deg_out[i], d = deg_in[i];
    rdo[i] = rsqrtf(o);
    rdi[i] = rsqrtf(d);
    idi[i] = 1.0f / d;  // self loops guarantee d >= 1
  }
}

__global__ void k_scan(const float* __restrict__ deg, int* __restrict__ off, int N, int E) {
  __shared__ int sm[1024];
  int tid = threadIdx.x;
  int chunk = (N + 1023) / 1024;
  int b = tid * chunk;
  int sum = 0;
  for (int j = 0; j < chunk; j++) { int i = b + j; if (i < N) sum += (int)deg[i]; }
  sm[tid] = sum;
  __syncthreads();
  for (int s = 1; s < 1024; s <<= 1) {
    int v = (tid >= s) ? sm[tid - s] : 0;
    __syncthreads();
    sm[tid] += v;
    __syncthreads();
  }
  int run = (tid == 0) ? 0 : sm[tid - 1];
  for (int j = 0; j < chunk; j++) {
    int i = b + j;
    if (i < N) { off[i] = run; run += (int)deg[i]; }
  }
  if (tid == 0) off[N] = E;
}

__global__ void k_fill(const int* __restrict__ src, const int* __restrict__ dst,
                       const int* __restrict__ off, int* cur,
                       const float* __restrict__ rdo, const float* __restrict__ rdi,
                       int* adj, float* aw, int E) {
  int e = blockIdx.x * blockDim.x + threadIdx.x;
  if (e < E) {
    int u = src[e], v = dst[e];
    int slot = off[v] + atomicAdd(&cur[v], 1);
    adj[slot] = u;
    aw[slot] = rdo[u] * rdi[v];
  }
}

// ---- batched W -> W^T bf16 hi/lo, LDS-tiled (coalesced read AND write) ----
// 5 matrices: W1,Wt1 (K=512, 128 tiles each), Wt2,Wp,W2 (K=256, 64 tiles each).
__global__ __launch_bounds__(256) void k_cvtW5(
    const float* __restrict__ Wa, const float* __restrict__ Wb, const float* __restrict__ Wc,
    const float* __restrict__ Wd, const float* __restrict__ We,
    unsigned short* Ha, unsigned short* Hb, unsigned short* Hc, unsigned short* Hd, unsigned short* He,
    unsigned short* La, unsigned short* Lb, unsigned short* Lc, unsigned short* Ld, unsigned short* Le) {
  int t = blockIdx.x;
  const float* W; unsigned short* H; unsigned short* L; int K, loc;
  if (t < 128)      { W = Wa; H = Ha; L = La; K = 512; loc = t; }
  else if (t < 256) { W = Wb; H = Hb; L = Lb; K = 512; loc = t - 128; }
  else if (t < 320) { W = Wc; H = Hc; L = Lc; K = 256; loc = t - 256; }
  else if (t < 384) { W = Wd; H = Hd; L = Ld; K = 256; loc = t - 320; }
  else              { W = We; H = He; L = Le; K = 256; loc = t - 384; }
  int kt = loc >> 3, ct = loc & 7;
  int k0 = kt * 32, c0 = ct * 32;
  __shared__ float T[32][33];
  int r = threadIdx.x >> 3, q = (threadIdx.x & 7) * 4;
  float4 v = *(const float4*)(W + (size_t)(k0 + r) * 256 + c0 + q);
  T[q + 0][r] = v.x; T[q + 1][r] = v.y; T[q + 2][r] = v.z; T[q + 3][r] = v.w;
  __syncthreads();
  float xs[4] = {T[r][q], T[r][q + 1], T[r][q + 2], T[r][q + 3]};
  ushort4 h, l;
  h.x = f2bf(xs[0]); l.x = f2bf(xs[0] - bf2f(h.x));
  h.y = f2bf(xs[1]); l.y = f2bf(xs[1] - bf2f(h.y));
  h.z = f2bf(xs[2]); l.z = f2bf(xs[2] - bf2f(h.z));
  h.w = f2bf(xs[3]); l.w = f2bf(xs[3] - bf2f(h.w));
  *(ushort4*)(H + (size_t)(c0 + r) * K + k0 + q) = h;
  *(ushort4*)(L + (size_t)(c0 + r) * K + k0 + q) = l;
}

// ---------------- split-bf16 MFMA GEMM: C[M,256] = A@W (+bias), A fp32 ----------------
// C = Ah@Wh + Ah@Wl + Al@Wh, fp32 acc (~6e-5 rel err). Unchanged (passing).
template <int K, bool BIAS>
__global__ __launch_bounds__(256, 2) void k_gemmM(
    const float* A,
    const unsigned short* __restrict__ Wth, const unsigned short* __restrict__ Wtl,
    const float* __restrict__ bias, float* C, int M) {
  __shared__ __align__(1024) char LB[2][32768];
  const int tid = threadIdx.x, wv = tid >> 6, ln = tid & 63;
  const int rg = wv & 1, ch = wv >> 1;
  const int i0 = blockIdx.x * 32;
  int arow = i0 + rg * 16 + (ln & 15);
  if (arow >= M) arow = M - 1;
  const int kg = ln >> 4;
  const float* Ar = A + (size_t)arow * K + kg * 8;

  auto STAGE = [&](int kc, int b) {
#pragma unroll
    for (int it = 0; it < 8; it++) {
      int idx = it * 4 + wv;
      int mat = idx >> 4, s = (idx >> 2) & 3, cb = idx & 3;
      const unsigned short* Wt = mat ? Wtl : Wth;
      const char* src = (const char*)(Wt + (size_t)(cb * 64 + ln) * K) + kc * 64 + s * 16;
      g2lds16(src, (char*)LB[b] + mat * 16384 + s * 4096 + cb * 1024);
    }
  };

  auto LOADA = [&](int t, bf16x8& ah, bf16x8& al) {
    float4 x0 = *(const float4*)(Ar + t * 32);
    float4 x1 = *(const float4*)(Ar + t * 32 + 4);
    float xs[8] = {x0.x, x0.y, x0.z, x0.w, x1.x, x1.y, x1.z, x1.w};
    union { u16x8 u; bf16x8 b; } hu, lu;
#pragma unroll
    for (int j = 0; j < 8; j++) {
      unsigned short h = f2bf(xs[j]);
      hu.u[j] = h;
      lu.u[j] = f2bf(xs[j] - bf2f(h));
    }
    ah = hu.b; al = lu.b;
  };

  constexpr int NC = K / 32;
  STAGE(0, 0);
  bf16x8 ah, al;
  LOADA(0, ah, al);
  f32x4 acc[8] = {};
  int b = 0;
  __syncthreads();
  for (int t = 0; t < NC; t++) {
    bf16x8 ah_n = ah, al_n = al;
    if (t + 1 < NC) {
      STAGE(t + 1, b ^ 1);
      LOADA(t + 1, ah_n, al_n);
    }
    const char* Lb = (const char*)LB[b];
    __builtin_amdgcn_s_setprio(1);
#pragma unroll
    for (int jf = 0; jf < 8; jf++) {
      int col = ch * 128 + jf * 16 + (ln & 15);
      bf16x8 bh = *(const bf16x8*)(Lb + kg * 4096 + col * 16);
      bf16x8 bl = *(const bf16x8*)(Lb + 16384 + kg * 4096 + col * 16);
      acc[jf] = __builtin_amdgcn_mfma_f32_16x16x32_bf16(ah, bh, acc[jf], 0, 0, 0);
      acc[jf] = __builtin_amdgcn_mfma_f32_16x16x32_bf16(al, bh, acc[jf], 0, 0, 0);
      acc[jf] = __builtin_amdgcn_mfma_f32_16x16x32_bf16(ah, bl, acc[jf], 0, 0, 0);
    }
    __builtin_amdgcn_s_setprio(0);
    __syncthreads();
    b ^= 1; ah = ah_n; al = al_n;
  }
#pragma unroll
  for (int i = 0; i < 4; i++) {
    int row = i0 + rg * 16 + kg * 4 + i;
    if (row < M) {
#pragma unroll
      for (int jf = 0; jf < 8; jf++) {
        int col = ch * 128 + jf * 16 + (ln & 15);
        float v = acc[jf][i];
        if constexpr (BIAS) v += bias[col];
        C[(size_t)row * 256 + col] = v;
      }
    }
  }
}

// ---------------- BatchNorm (train) stats + apply + relu ----------------
__global__ void k_bnstat(const float* __restrict__ T, float* s, float* ss, int M) {
  int c = threadIdx.x;
  int r0 = blockIdx.x * 64;
  float a = 0, b = 0;
  for (int r = r0; r < r0 + 64 && r < M; r++) {
    float v = T[(size_t)r * 256 + c];
    a += v; b += v * v;
  }
  atomicAdd(&s[c], a);
  atomicAdd(&ss[c], b);
}

__global__ void k_bnrelu(float* T, const float* __restrict__ s, const float* __restrict__ ss,
                         const float* __restrict__ g, const float* __restrict__ b, int M) {
  int r = blockIdx.x, c = threadIdx.x;
  float invM = 1.0f / (float)M;
  float mu = s[c] * invM;
  float var = ss[c] * invM - mu * mu;
  float w = rsqrtf(var + 1e-5f) * g[c];
  float v = T[(size_t)r * 256 + c];
  v = (v - mu) * w + b[c];
  T[(size_t)r * 256 + c] = fmaxf(v, 0.0f);
}

// ---- column-sliced CSR gather: Y[v] = sum_e w*X[src] (+bias)(relu), 64-col slices ----
template <bool UNIT, bool RELU>
__global__ __launch_bounds__(256) void k_aggS(
    const float* __restrict__ X, const int* __restrict__ off, const int* __restrict__ adj,
    const float* __restrict__ w, const float* __restrict__ bias, float* __restrict__ Y,
    int N, int NV) {
  int slice = blockIdx.x / NV, vc = blockIdx.x - slice * NV;
  int wv = threadIdx.x >> 6, ln = threadIdx.x & 63;
  int v = vc * 4 + wv;
  if (v >= N) return;
  int c = slice * 64 + ln;
  int s0 = off[v], s1 = off[v + 1];
  float acc = 0.f;
  int s = s0;
  for (; s + 3 < s1; s += 4) {
    int u0 = adj[s], u1 = adj[s + 1], u2 = adj[s + 2], u3 = adj[s + 3];
    float x0 = X[(size_t)u0 * 256 + c], x1 = X[(size_t)u1 * 256 + c];
    float x2 = X[(size_t)u2 * 256 + c], x3 = X[(size_t)u3 * 256 + c];
    if constexpr (UNIT) acc += (x0 + x1) + (x2 + x3);
    else acc += w[s] * x0 + w[s + 1] * x1 + w[s + 2] * x2 + w[s + 3] * x3;
  }
  for (; s < s1; s++) {
    float wt = UNIT ? 1.f : w[s];
    acc += wt * X[(size_t)adj[s] * 256 + c];
  }
  if constexpr (!UNIT) acc += bias[c];
  if constexpr (RELU) acc = fmaxf(acc, 0.f);
  Y[(size_t)v * 256 + c] = acc;
}

// ------- row L2-normalize (in place) + scaled bf16 copy, BOTH z and q in one launch -------
__global__ __launch_bounds__(256) void k_norm2(float* X0, unsigned short* Xb0,
                                               float* X1, unsigned short* Xb1,
                                               int N, int NPAD) {
  int wv = threadIdx.x >> 6, ln = threadIdx.x & 63;
  int r = blockIdx.x * 4 + wv;
  if (r >= NPAD) return;
#pragma unroll
  for (int which = 0; which < 2; which++) {
    float* X = which ? X1 : X0;
    unsigned short* Xb = which ? Xb1 : Xb0;
    if (r >= N) {
      ushort4 z = {0, 0, 0, 0};
      ((ushort4*)Xb)[(size_t)r * 64 + ln] = z;
      continue;
    }
    float4 x = ((const float4*)X)[(size_t)r * 64 + ln];
    float ss = x.x * x.x + x.y * x.y + x.z * x.z + x.w * x.w;
#pragma unroll
    for (int m = 1; m < 64; m <<= 1) ss += __shfl_xor(ss, m, 64);
    float sc = 1.0f / fmaxf(sqrtf(ss), 1e-12f);
    float4 xn = {x.x * sc, x.y * sc, x.z * sc, x.w * sc};
    ((float4*)X)[(size_t)r * 64 + ln] = xn;
    float bs = sc * SSCALE;
    ushort4 b;
    b.x = f2bf(x.x * bs); b.y = f2bf(x.y * bs);
    b.z = f2bf(x.z * bs); b.w = f2bf(x.w * bs);
    ((ushort4*)Xb)[(size_t)r * 64 + ln] = b;
  }
}

// ---------------- similarity row-sums, Z-part triangular via symmetry ----------------
// S1 = rowsums exp(Z Z^T/T): symmetric -> only j0 >= i0 tiles. Strictly-above tiles
// (j0 >= i0+256) also credit col-sums (atomicAdd S1[col] with the same exp values =
// transpose entries). Diagonal 256-band: full square, row-sums only. Pad rows live in
// the last i-block -> never emit col credits; pad cols add exactly PADF ones per row
// (subtracted in k_final). S2 = rowsums exp(Z Q^T/T): full range. MFMA acc is the
// natural-log exp argument (SSCALE fold); __expf = v_mul+v_exp_f32, |arg| <= ~2.
__global__ __launch_bounds__(256, 2) void k_sim(const unsigned short* __restrict__ Zb,
                                                const unsigned short* __restrict__ Qb,
                                                float* __restrict__ S1, float* __restrict__ S2,
                                                int N, int JT, int JS) {
  __shared__ __align__(1024) char LB[2][32768];
  const int tid = threadIdx.x;
  const int wv = tid >> 6, ln = tid & 63;
  const int i0 = blockIdx.x * 256;
  const int wb = wv * 64;

  auto STAGE = [&](int jt, int b, bool qonly) {
    int j0 = jt * 32;
    char* Lb = (char*)LB[b];
#pragma unroll
    for (int it = 0; it < 8; it++) {
      if (qonly && it < 4) continue;       // chunks c<16 hold Z rows — never read
      int c = it * 4 + wv;
      int L = c * 1024 + ln * 16;
      int r = L >> 9;                      // 0..31 Z rows, 32..63 Q rows
      int o = (L & 511) ^ ((r & 7) << 4);
      const char* g = (r < 32) ? (const char*)Zb + (size_t)(j0 + r) * 512 + o
                               : (const char*)Qb + (size_t)(j0 + r - 32) * 512 + o;
      g2lds16(g, Lb + c * 1024);
    }
  };

  int jt0 = (blockIdx.y * JT) / JS;
  int jt1 = ((blockIdx.y + 1) * JT) / JS;

  STAGE(jt0, 0, jt0 * 32 < i0);

  // A fragments from global: wave owns rows i0+wb..+63 (4 rowfrags), K=256
  bf16x8 af[4][8];
#pragma unroll
  for (int rf = 0; rf < 4; rf++) {
    const char* arow = (const char*)(Zb + (size_t)(i0 + wb + rf * 16 + (ln & 15)) * 256);
#pragma unroll
    for (int kk = 0; kk < 8; kk++)
      af[rf][kk] = *(const bf16x8*)(arow + kk * 64 + ((ln >> 4) << 4));
  }

  f32x4 rs[4][2] = {};  // row-sum accumulators [rowfrag][mat]

  __syncthreads();
  int cur = 0;
  for (int jt = jt0; jt < jt1; jt++) {
    int j0 = jt * 32;
    bool zyes = (j0 >= i0);
    if (jt + 1 < jt1) STAGE(jt + 1, cur ^ 1, (jt + 1) * 32 < i0);
    const char* Lb = (const char*)LB[cur];

    if (zyes) {  // ---- Z phase (triangular) ----
      f32x4 acc[4][2] = {};
      __builtin_amdgcn_s_setprio(1);
#pragma unroll
      for (int kk = 0; kk < 8; kk++) {
#pragma unroll
        for (int cf = 0; cf < 2; cf++) {
          int brow = cf * 16 + (ln & 15);
          int o = (kk * 64 + ((ln >> 4) << 4)) ^ ((brow & 7) << 4);
          bf16x8 bb = *(const bf16x8*)(Lb + brow * 512 + o);
#pragma unroll
          for (int rf = 0; rf < 4; rf++)
            acc[rf][cf] = __builtin_amdgcn_mfma_f32_16x16x32_bf16(af[rf][kk], bb, acc[rf][cf], 0, 0, 0);
        }
      }
      __builtin_amdgcn_s_setprio(0);
      bool zfull = (j0 >= i0 + 256);
      float cs0 = 0.f, cs1 = 0.f;
#pragma unroll
      for (int rf = 0; rf < 4; rf++)
#pragma unroll
        for (int i = 0; i < 4; i++) {
          float e0 = __expf(acc[rf][0][i]);
          float e1 = __expf(acc[rf][1][i]);
          rs[rf][0][i] += e0 + e1;
          if (zfull) { cs0 += e0; cs1 += e1; }
        }
      if (zfull) {  // col credits: col j gets this wave's 64 i-row contributions
        cs0 += __shfl_xor(cs0, 16, 64); cs0 += __shfl_xor(cs0, 32, 64);
        cs1 += __shfl_xor(cs1, 16, 64); cs1 += __shfl_xor(cs1, 32, 64);
        if (ln < 16) {
          int c0 = j0 + ln, c1 = j0 + 16 + ln;
          if (c0 < N) atomicAdd(S1 + c0, cs0);
          if (c1 < N) atomicAdd(S1 + c1, cs1);
        }
      }
    }

    {  // ---- Q phase (full) ----
      f32x4 acc[4][2] = {};
      __builtin_amdgcn_s_setprio(1);
#pragma unroll
      for (int kk = 0; kk < 8; kk++) {
#pragma unroll
        for (int cf = 0; cf < 2; cf++) {
          int brow = 32 + cf * 16 + (ln & 15);
          int o = (kk * 64 + ((ln >> 4) << 4)) ^ ((brow & 7) << 4);
          bf16x8 bb = *(const bf16x8*)(Lb + brow * 512 + o);
#pragma unroll
          for (int rf = 0; rf < 4; rf++)
            acc[rf][cf] = __builtin_amdgcn_mfma_f32_16x16x32_bf16(af[rf][kk], bb, acc[rf][cf], 0, 0, 0);
        }
      }
      __builtin_amdgcn_s_setprio(0);
#pragma unroll
      for (int rf = 0; rf < 4; rf++)
#pragma unroll
        for (int i = 0; i < 4; i++)
          rs[rf][1][i] += __expf(acc[rf][0][i]) + __expf(acc[rf][1][i]);
    }

    __syncthreads();
    cur ^= 1;
  }

  // row-sum reduction: 16 lanes (same ln>>4 group) share each output row
#pragma unroll
  for (int rf = 0; rf < 4; rf++)
#pragma unroll
    for (int m = 0; m < 2; m++)
#pragma unroll
      for (int i = 0; i < 4; i++) {
        float v = rs[rf][m][i];
        v += __shfl_xor(v, 1, 64);
        v += __shfl_xor(v, 2, 64);
        v += __shfl_xor(v, 4, 64);
        v += __shfl_xor(v, 8, 64);
        if ((ln & 15) == 0) {
          int row = i0 + wb + rf * 16 + ((ln >> 4) << 2) + i;
          if (row < N) atomicAdd(((m == 0) ? S1 : S2) + row, v);
        }
      }
}

// ---------------- final loss ----------------
__global__ __launch_bounds__(256) void k_final(const float* __restrict__ zsum, const float* __restrict__ q,
                                               const float* __restrict__ S1, const float* __restrict__ S2,
                                               const int* __restrict__ off, const int* __restrict__ adj,
                                               const float* __restrict__ idi, float* __restrict__ out,
                                               int N, float pad) {
  int wv = threadIdx.x >> 6, ln = threadIdx.x & 63;
  int v = blockIdx.x * 4 + wv;
  if (v >= N) return;
  float4 zs = ((const float4*)zsum)[(size_t)v * 64 + ln];
  float4 qv = ((const float4*)q)[(size_t)v * 64 + ln];
  float d = zs.x * qv.x + zs.y * qv.y + zs.z * qv.z + zs.w * qv.w;
  float s1v = S1[v] - pad;
  float lg = 0.0f;
  int e0 = off[v], e1 = off[v + 1];
  for (int s = e0 + ln; s < e1; s += 64) {
    int u = adj[s];
    lg += __logf(s1v + LAMC * (S2[u] - pad));
  }
#pragma unroll
  for (int m = 1; m < 64; m <<= 1) {
    d += __shfl_xor(d, m, 64);
    lg += __shfl_xor(lg, m, 64);
  }
  if (ln == 0) {
    float inv = idi[v];
    float posv = d * inv * TEMP_INV;
    float negv = lg * inv;
    atomicAdd(out, (negv - posv) * (1.0f / (float)N));
  }
}

// ---------------- host ----------------
extern "C" void kernel_launch(void* const* d_in, const int* in_sizes, int n_in,
                              void* d_out, int out_size, void* d_ws, size_t ws_size,
                              hipStream_t stream) {
  const float* feat  = (const float*)d_in[0];
  const float* W1    = (const float*)d_in[1];
  const float* b1    = (const float*)d_in[2];
  const float* W2    = (const float*)d_in[3];
  const float* b2    = (const float*)d_in[4];
  const float* Wt1   = (const float*)d_in[5];
  const float* bt1   = (const float*)d_in[6];
  const float* gamma = (const float*)d_in[7];
  const float* beta  = (const float*)d_in[8];
  const float* Wt2   = (const float*)d_in[9];
  const float* bt2   = (const float*)d_in[10];
  const float* Wp    = (const float*)d_in[11];
  const float* bp    = (const float*)d_in[12];
  const int*   src   = (const int*)d_in[13];
  const int*   dst   = (const int*)d_in[14];
  const int N = in_sizes[0] / 512;
  const int E = in_sizes[13];
  const int NTI = (N + 255) / 256, NPAD = NTI * 256, JT = NPAD / 32;
  const int JS = 25;
  const float PADF = (float)(NPAD - N);

  char* p = (char*)d_ws;
  auto alloc = [&](size_t bytes) { char* r = p; p += (bytes + 255) & ~(size_t)255; return r; };
  float* B0 = (float*)alloc((size_t)N * 256 * 4);            // xw1 -> xw2 -> zsum
  float* B1 = (float*)alloc((size_t)N * 256 * 4);            // t -> tr -> trans -> p -> q
  float* B2 = (float*)alloc((size_t)N * 256 * 4);            // h1 -> h2 -> z
  unsigned short* zb = (unsigned short*)alloc((size_t)NPAD * 256 * 2);
  unsigned short* qb = (unsigned short*)alloc((size_t)NPAD * 256 * 2);
  // per-weight W^T bf16 hi/lo: W1,Wt1 (K=512), Wt2,Wp,W2 (K=256)
  unsigned short* wh[5]; unsigned short* wl[5];
  const int KS[5] = {512, 512, 256, 256, 256};
  for (int i = 0; i < 5; i++) {
    wh[i] = (unsigned short*)alloc((size_t)256 * KS[i] * 2);
    wl[i] = (unsigned short*)alloc((size_t)256 * KS[i] * 2);
  }
  int*   off = (int*)alloc((size_t)(N + 1) * 4);
  int*   adj = (int*)alloc((size_t)E * 4);
  float* aw  = (float*)alloc((size_t)E * 4);
  char*  zblk = p;                                           // zeroed each launch
  float* deg_out = (float*)alloc((size_t)N * 4);
  float* deg_in  = (float*)alloc((size_t)N * 4);
  int*   cur     = (int*)alloc((size_t)N * 4);
  float* S1 = (float*)alloc((size_t)N * 4);
  float* S2 = (float*)alloc((size_t)N * 4);
  float* bns  = (float*)alloc(256 * 4);
  float* bnss = (float*)alloc(256 * 4);
  size_t zbytes = (size_t)(p - zblk);
  float* rdo = (float*)alloc((size_t)N * 4);
  float* rdi = (float*)alloc((size_t)N * 4);
  float* idi = (float*)alloc((size_t)N * 4);
  (void)ws_size; (void)n_in; (void)out_size;

  hipMemsetAsync(zblk, 0, zbytes, stream);
  hipMemsetAsync(d_out, 0, 4, stream);

  int gE = (E + 255) / 256, gN = (N + 255) / 256;
  int NV = (N + 3) / 4, gw = NV, gm = (N + 31) / 32;

  k_cvtW5<<<448, 256, 0, stream>>>(W1, Wt1, Wt2, Wp, W2,
                                   wh[0], wh[1], wh[2], wh[3], wh[4],
                                   wl[0], wl[1], wl[2], wl[3], wl[4]);

  k_deg<<<gE, 256, 0, stream>>>(src, dst, deg_out, deg_in, E);
  k_rdeg<<<gN, 256, 0, stream>>>(deg_out, deg_in, rdo, rdi, idi, N);
  k_scan<<<1, 1024, 0, stream>>>(deg_in, off, N, E);
  k_fill<<<gE, 256, 0, stream>>>(src, dst, off, cur, rdo, rdi, adj, aw, E);

  k_gemmM<512, false><<<gm, 256, 0, stream>>>(feat, wh[0], wl[0], nullptr, B0, N);  // xw1
  k_gemmM<512, true ><<<gm, 256, 0, stream>>>(feat, wh[1], wl[1], bt1, B1, N);      // t

  k_bnstat<<<(N + 63) / 64, 256, 0, stream>>>(B1, bns, bnss, N);
  k_bnrelu<<<N, 256, 0, stream>>>(B1, bns, bnss, gamma, beta, N);                   // tr

  k_gemmM<256, true ><<<gm, 256, 0, stream>>>(B1, wh[2], wl[2], bt2, B1, N);        // trans (in place)
  k_gemmM<256, true ><<<gm, 256, 0, stream>>>(B1, wh[3], wl[3], bp, B1, N);         // p (in place)

  k_aggS<false, true ><<<4 * gw, 256, 0, stream>>>(B0, off, adj, aw, b1, B2, N, NV);  // h1
  k_gemmM<256, false><<<gm, 256, 0, stream>>>(B2, wh[4], wl[4], nullptr, B0, N);      // xw2
  k_aggS<false, false><<<4 * gw, 256, 0, stream>>>(B0, off, adj, aw, b2, B2, N, NV);  // h2

  int gnp = (NPAD + 3) / 4;
  k_norm2<<<gnp, 256, 0, stream>>>(B2, zb, B1, qb, N, NPAD);  // z + zb ; q + qb

  dim3 gs(NTI, JS);
  k_sim<<<gs, 256, 0, stream>>>(zb, qb, S1, S2, N, JT, JS);

  k_aggS<true, false><<<4 * gw, 256, 0, stream>>>(B2, off, adj, aw, nullptr, B0, N, NV);  // zsum
  k_final<<<gw, 256, 0, stream>>>(B0, B1, S1, S2, off, adj, idi, (float*)d_out, N, PADF);
}